// Round 8
// baseline (539.392 us; speedup 1.0000x reference)
//
#include <hip/hip_runtime.h>

#define N_NODES 50000
#define N_EDGES 640000
#define HID 128
#define EDGE_DIM 32
#define NUM_GRAPHS 512
#define BN_EPS 1e-5f
#define NGRP16 3125    // N_NODES / 16 (exact)
#define NSCB 49        // ceil(N_NODES/1024)

typedef unsigned int uint32;
typedef unsigned short ushort16;

// round-to-nearest-even f32 -> bf16 bits
__device__ inline ushort16 f2bf(float x) {
    uint32 u = __float_as_uint(x);
    return (ushort16)((u + 0x7fff + ((u >> 16) & 1)) >> 16);
}

__device__ inline float rdlane(float v, int lane) {
    return __int_as_float(__builtin_amdgcn_readlane(__float_as_int(v), lane));
}

// ---------------------------------------------------------------------------
// deg[d] = number of edges with dst == d
// ---------------------------------------------------------------------------
__global__ void deg_hist_kernel(const int* __restrict__ eidx, int* __restrict__ deg) {
    int e = blockIdx.x * 256 + threadIdx.x;
    if (e >= N_EDGES) return;
    atomicAdd(&deg[eidx[N_EDGES + e]], 1);
}

// ---------------------------------------------------------------------------
// Parallel exclusive scan of deg -> rowp, 3 dispatches
// ---------------------------------------------------------------------------
__global__ void scan_part1_kernel(const int* __restrict__ deg, int* __restrict__ bsum) {
    __shared__ int ts[256];
    int tid = threadIdx.x;
    int base = blockIdx.x * 1024 + tid * 4;
    int s = 0;
    #pragma unroll
    for (int j = 0; j < 4; ++j) { int i = base + j; if (i < N_NODES) s += deg[i]; }
    ts[tid] = s;
    __syncthreads();
    for (int off = 128; off > 0; off >>= 1) {
        if (tid < off) ts[tid] += ts[tid + off];
        __syncthreads();
    }
    if (tid == 0) bsum[blockIdx.x] = ts[0];
}

__global__ void scan_part2_kernel(const int* __restrict__ bsum, int* __restrict__ boff) {
    __shared__ int b[64];
    int t = threadIdx.x;
    b[t] = (t < NSCB) ? bsum[t] : 0;
    __syncthreads();
    if (t == 0) {
        int run = 0;
        for (int i = 0; i < NSCB; ++i) { int x = b[i]; b[i] = run; run += x; }
    }
    __syncthreads();
    if (t < NSCB) boff[t] = b[t];
}

__global__ void scan_part3_kernel(const int* __restrict__ deg, const int* __restrict__ boff,
                                  int* __restrict__ rowp) {
    __shared__ int ts[256];
    int tid = threadIdx.x;
    int base = blockIdx.x * 1024 + tid * 4;
    int v[4];
    int s = 0;
    #pragma unroll
    for (int j = 0; j < 4; ++j) {
        int i = base + j;
        v[j] = (i < N_NODES) ? deg[i] : 0;
        s += v[j];
    }
    ts[tid] = s;
    __syncthreads();
    for (int off = 1; off < 256; off <<= 1) {
        int t = (tid >= off) ? ts[tid - off] : 0;
        __syncthreads();
        ts[tid] += t;
        __syncthreads();
    }
    int excl = boff[blockIdx.x] + ts[tid] - s;
    #pragma unroll
    for (int j = 0; j < 4; ++j) {
        int i = base + j;
        if (i < N_NODES) rowp[i] = excl;
        excl += v[j];
    }
    if (blockIdx.x == 0 && tid == 0) rowp[N_NODES] = N_EDGES;
}

// CSR fill: csr_src[p] = source node, csr_eid[p] = edge id
__global__ void fill_csr_kernel(const int* __restrict__ eidx,
                                const int* __restrict__ rowp,
                                int* __restrict__ cursor,
                                int* __restrict__ csr_src,
                                int* __restrict__ csr_eid) {
    int e = blockIdx.x * 256 + threadIdx.x;
    if (e >= N_EDGES) return;
    int d = eidx[N_EDGES + e];
    int pos = rowp[d] + atomicAdd(&cursor[d], 1);
    csr_src[pos] = eidx[e];
    csr_eid[pos] = e;
}

// ---------------------------------------------------------------------------
// Ea[d] = sum of edge_attr rows with dst == d (CSR gather, no float atomics)
// half-wave per node, 4-deep index prefetch + 4 independent accumulators
// ---------------------------------------------------------------------------
__global__ __launch_bounds__(256) void ea_gather_kernel(
        const float* __restrict__ edge_attr,
        const int* __restrict__ rowp,
        const int* __restrict__ csr_eid,
        float* __restrict__ Ea) {
    int node = blockIdx.x * 8 + (threadIdx.x >> 5);
    int c = threadIdx.x & 31;
    if (node >= N_NODES) return;
    int beg = rowp[node], end = rowp[node + 1];
    float s0 = 0.f, s1 = 0.f, s2 = 0.f, s3 = 0.f;
    int p = beg;
    for (; p + 4 <= end; p += 4) {
        int e0 = csr_eid[p],     e1 = csr_eid[p + 1];
        int e2 = csr_eid[p + 2], e3 = csr_eid[p + 3];
        s0 += edge_attr[e0 * EDGE_DIM + c];
        s1 += edge_attr[e1 * EDGE_DIM + c];
        s2 += edge_attr[e2 * EDGE_DIM + c];
        s3 += edge_attr[e3 * EDGE_DIM + c];
    }
    for (; p < end; ++p)
        s0 += edge_attr[csr_eid[p] * EDGE_DIM + c];
    Ea[node * EDGE_DIM + c] = (s0 + s1) + (s2 + s3);
}

// ---------------------------------------------------------------------------
// GEMM v3 — readlane register scheme. Per layer:
//   xin    = BN ? relu(X*scale + shift) : X
//   h[i]   = xin[i] @ Wn + bn      -> bf16 (gather operand)
//   acc[i] = h[i] + Ea[i] @ We + deg[i] * be   -> fp32
// 1024 threads = 16 waves. Wave owns 16 rows (wave-uniform); lane owns
// cols (2L, 2L+1). X staged in REGISTERS: lane L holds x[r][2L:2L+2] for
// r=0..15. Inner loop per k: 1 ds_read_b64 (w cols) + per-row v_readlane
// (x scalar -> SGPR, legal scalar FMA operand). No Xs LDS at all.
// Ea staged likewise (lane L: rows (L>>4)*4+j, k=(L&15)*2).
// Group interleave g = blk + 256*wid spreads 3125 groups over all CUs.
// LDS: 64K Wn + 16K We = 80 KB.
// ---------------------------------------------------------------------------
template <bool BN>
__global__ __launch_bounds__(1024) void gemm_v3_kernel(
        const float* __restrict__ X, const float* __restrict__ Wn,
        const float* __restrict__ bnb,
        const float* __restrict__ Ea, const float* __restrict__ We,
        const float* __restrict__ be, const int* __restrict__ deg,
        const float* __restrict__ scale, const float* __restrict__ shift,
        uint32* __restrict__ hb32, float* __restrict__ acc) {
    __shared__ __align__(16) float Wns[128 * 128];   // [k][c], 64 KB
    __shared__ __align__(16) float Wes[32 * 128];    // [k][c], 16 KB
    const int tid = threadIdx.x;

    #pragma unroll
    for (int j = 0; j < 4; ++j)
        ((float4*)Wns)[tid + j * 1024] = ((const float4*)Wn)[tid + j * 1024];
    ((float4*)Wes)[tid] = ((const float4*)We)[tid];
    __syncthreads();

    const int wid = tid >> 6, L = tid & 63;
    const int g = blockIdx.x + 256 * wid;    // wave-major interleave
    if (g >= NGRP16) return;
    const int r0 = g * 16;

    // ---- stage 16 rows x float2 (lane's 2 cols) into registers, apply BN ----
    float2 x2[16];
    float2 sc2, sh2;
    if (BN) {
        sc2 = *(const float2*)&scale[2 * L];
        sh2 = *(const float2*)&shift[2 * L];
    }
    #pragma unroll
    for (int r = 0; r < 16; ++r) {
        float2 v = *(const float2*)&X[(r0 + r) * 128 + 2 * L];
        if (BN) {
            v.x = fmaxf(0.f, v.x * sc2.x + sh2.x);
            v.y = fmaxf(0.f, v.y * sc2.y + sh2.y);
        }
        x2[r] = v;
    }

    float2 a2[16];
    #pragma unroll
    for (int r = 0; r < 16; ++r) a2[r] = make_float2(0.f, 0.f);

    // ---- node GEMM: K = 128 (k = 2*kk, 2*kk+1) ----
    #pragma unroll 4
    for (int kk = 0; kk < 64; ++kk) {
        float2 w0 = *(const float2*)&Wns[(2 * kk) * 128 + 2 * L];
        float2 w1 = *(const float2*)&Wns[(2 * kk + 1) * 128 + 2 * L];
        #pragma unroll
        for (int r = 0; r < 16; ++r) {
            float sx = rdlane(x2[r].x, kk);   // x[r][2kk]
            float sy = rdlane(x2[r].y, kk);   // x[r][2kk+1]
            a2[r].x = fmaf(sx, w0.x, a2[r].x);
            a2[r].y = fmaf(sx, w0.y, a2[r].y);
            a2[r].x = fmaf(sy, w1.x, a2[r].x);
            a2[r].y = fmaf(sy, w1.y, a2[r].y);
        }
    }

    // h = a + bn -> packed bf16 (layout matches gather: hb32[row*64+L])
    const float2 bn2 = *(const float2*)&bnb[2 * L];
    #pragma unroll
    for (int r = 0; r < 16; ++r) {
        a2[r].x += bn2.x; a2[r].y += bn2.y;
        hb32[(r0 + r) * 64 + L] =
            (uint32)f2bf(a2[r].x) | ((uint32)f2bf(a2[r].y) << 16);
    }

    // ---- edge GEMM: K = 32, Ea register-staged ----
    // lane L holds Ea[r0 + (L>>4)*4 + j][2*(L&15) : +2] in e2[j]
    float2 e2[4];
    #pragma unroll
    for (int j = 0; j < 4; ++j)
        e2[j] = *(const float2*)&Ea[(r0 + (L >> 4) * 4 + j) * 32 + (L & 15) * 2];

    #pragma unroll 2
    for (int kk = 0; kk < 16; ++kk) {
        float2 w0 = *(const float2*)&Wes[(2 * kk) * 128 + 2 * L];
        float2 w1 = *(const float2*)&Wes[(2 * kk + 1) * 128 + 2 * L];
        #pragma unroll
        for (int r = 0; r < 16; ++r) {
            int srcl = ((r >> 2) << 4) | kk;        // lane holding Ea[r][2kk]
            float sx = rdlane(e2[r & 3].x, srcl);
            float sy = rdlane(e2[r & 3].y, srcl);
            a2[r].x = fmaf(sx, w0.x, a2[r].x);
            a2[r].y = fmaf(sx, w0.y, a2[r].y);
            a2[r].x = fmaf(sy, w1.x, a2[r].x);
            a2[r].y = fmaf(sy, w1.y, a2[r].y);
        }
    }

    const float2 be2 = *(const float2*)&be[2 * L];
    #pragma unroll
    for (int r = 0; r < 16; ++r) {
        float dg = (float)deg[r0 + r];
        float2 o;
        o.x = a2[r].x + dg * be2.x;
        o.y = a2[r].y + dg * be2.y;
        *(float2*)&acc[(r0 + r) * 128 + 2 * L] = o;
    }
}

// ---------------------------------------------------------------------------
// acc[d] += sum over CSR edges of h_bf16[src]
// one WAVE (64 lanes) per node; lane covers cols (2*lane, 2*lane+1);
// 4-deep index prefetch + 4 independent partial sums for MLP
// ---------------------------------------------------------------------------
__global__ __launch_bounds__(256) void gather_kernel(
        const uint32* __restrict__ h32,      // 64 uints (=128 bf16) per row
        const int* __restrict__ rowp, const int* __restrict__ csr_src,
        float* __restrict__ acc) {
    int node = blockIdx.x * 4 + (threadIdx.x >> 6);
    if (node >= N_NODES) return;
    int lane = threadIdx.x & 63;
    int beg = rowp[node], end = rowp[node + 1];
    float sx0 = 0.f, sy0 = 0.f, sx1 = 0.f, sy1 = 0.f;
    float sx2 = 0.f, sy2 = 0.f, sx3 = 0.f, sy3 = 0.f;
    int p = beg;
    for (; p + 4 <= end; p += 4) {
        int i0 = csr_src[p], i1 = csr_src[p + 1];
        int i2 = csr_src[p + 2], i3 = csr_src[p + 3];
        uint32 v0 = h32[i0 * 64 + lane];
        uint32 v1 = h32[i1 * 64 + lane];
        uint32 v2 = h32[i2 * 64 + lane];
        uint32 v3 = h32[i3 * 64 + lane];
        sx0 += __uint_as_float(v0 << 16); sy0 += __uint_as_float(v0 & 0xffff0000u);
        sx1 += __uint_as_float(v1 << 16); sy1 += __uint_as_float(v1 & 0xffff0000u);
        sx2 += __uint_as_float(v2 << 16); sy2 += __uint_as_float(v2 & 0xffff0000u);
        sx3 += __uint_as_float(v3 << 16); sy3 += __uint_as_float(v3 & 0xffff0000u);
    }
    for (; p < end; ++p) {
        uint32 v = h32[csr_src[p] * 64 + lane];
        sx0 += __uint_as_float(v << 16); sy0 += __uint_as_float(v & 0xffff0000u);
    }
    float2* ap = (float2*)&acc[node * 128 + lane * 2];
    float2 a = *ap;
    a.x += (sx0 + sx1) + (sx2 + sx3);
    a.y += (sy0 + sy1) + (sy2 + sy3);
    *ap = a;
}

// per-column sum / sumsq over all nodes
__global__ void stats_kernel(const float* __restrict__ acc,
                             float* __restrict__ cs, float* __restrict__ cq) {
    int c = threadIdx.x & 127;
    int rg = threadIdx.x >> 7;
    float s = 0.f, q = 0.f;
    for (int r = blockIdx.x * 2 + rg; r < N_NODES; r += gridDim.x * 2) {
        float v = acc[r * 128 + c];
        s += v; q += v * v;
    }
    unsafeAtomicAdd(&cs[c], s);
    unsafeAtomicAdd(&cq[c], q);
}

// scale/shift from column stats: y = x*scale[c] + shift[c]
__global__ void prep_bn_kernel(const float* __restrict__ cs, const float* __restrict__ cq,
                               const float* __restrict__ gamma, const float* __restrict__ beta,
                               float* __restrict__ scale, float* __restrict__ shift) {
    int c = threadIdx.x;
    const float invN = 1.0f / (float)N_NODES;
    float m = cs[c] * invN;
    float var = cq[c] * invN - m * m;
    float sc = gamma[c] * rsqrtf(var + BN_EPS);
    scale[c] = sc;
    shift[c] = beta[c] - m * sc;
}

// ---------------------------------------------------------------------------
// One block per graph (batch is sorted): binary-search node range, apply
// layer-3 BN+ReLU inline, mean-pool, then the 128->2 FC. No atomics.
// ---------------------------------------------------------------------------
__global__ __launch_bounds__(256) void pool_fc_kernel(
        const float* __restrict__ acc,
        const float* __restrict__ scale, const float* __restrict__ shift,
        const int* __restrict__ batch,
        const float* __restrict__ Wfc, const float* __restrict__ bfc,
        float* __restrict__ out) {
    __shared__ float ps[256];
    int g = blockIdx.x;
    int lo = 0, hi = N_NODES;
    while (lo < hi) { int mid = (lo + hi) >> 1; if (batch[mid] < g) lo = mid + 1; else hi = mid; }
    int start = lo;
    hi = N_NODES;
    while (lo < hi) { int mid = (lo + hi) >> 1; if (batch[mid] < g + 1) lo = mid + 1; else hi = mid; }
    int end = lo;

    int c = threadIdx.x & 127;
    int half = threadIdx.x >> 7;
    float sc = scale[c], sh = shift[c];
    float s = 0.f;
    for (int r = start + half; r < end; r += 2)
        s += fmaxf(0.f, acc[r * 128 + c] * sc + sh);
    ps[threadIdx.x] = s;
    __syncthreads();
    if (half == 0)
        ps[c] = (ps[c] + ps[c + 128]) / fmaxf((float)(end - start), 1.0f);
    __syncthreads();
    if (threadIdx.x < 2) {
        int o = threadIdx.x;
        float t = 0.f;
        #pragma unroll 16
        for (int cc = 0; cc < 128; ++cc) t += ps[cc] * Wfc[cc * 2 + o];
        out[g * 2 + o] = t + bfc[o];
    }
}

// ---------------------------------------------------------------------------
extern "C" void kernel_launch(void* const* d_in, const int* in_sizes, int n_in,
                              void* d_out, int out_size, void* d_ws, size_t ws_size,
                              hipStream_t stream) {
    const float* x         = (const float*)d_in[0];
    const float* edge_attr = (const float*)d_in[1];
    const int*   eidx      = (const int*)d_in[2];
    const int*   batch     = (const int*)d_in[3];
    const float* Wn[3]  = {(const float*)d_in[4],  (const float*)d_in[8],  (const float*)d_in[12]};
    const float* bnb[3] = {(const float*)d_in[5],  (const float*)d_in[9],  (const float*)d_in[13]};
    const float* We[3]  = {(const float*)d_in[6],  (const float*)d_in[10], (const float*)d_in[14]};
    const float* be[3]  = {(const float*)d_in[7],  (const float*)d_in[11], (const float*)d_in[15]};
    const float* gm[3]  = {(const float*)d_in[16], (const float*)d_in[18], (const float*)d_in[20]};
    const float* bt[3]  = {(const float*)d_in[17], (const float*)d_in[19], (const float*)d_in[21]};
    const float* Wfc = (const float*)d_in[22];
    const float* bfc = (const float*)d_in[23];
    float* out = (float*)d_out;

    char* p = (char*)d_ws;
    auto alloc = [&](size_t bytes) {
        char* q = p;
        p += (bytes + 255) & ~size_t(255);
        return q;
    };
    float*  Ea     = (float*)alloc(sizeof(float) * N_NODES * EDGE_DIM);
    uint32* hbuf   = (uint32*)alloc(sizeof(uint32) * N_NODES * 64);   // bf16x2 packed
    float*  accA   = (float*)alloc(sizeof(float) * N_NODES * HID);
    float*  accB   = (float*)alloc(sizeof(float) * N_NODES * HID);
    float*  cs     = (float*)alloc(sizeof(float) * HID);    // cs and cq contiguous
    float*  cq     = (float*)alloc(sizeof(float) * HID);
    float*  scale  = (float*)alloc(sizeof(float) * HID);
    float*  shift  = (float*)alloc(sizeof(float) * HID);
    int*    deg    = (int*)alloc(sizeof(int) * N_NODES);
    int*    rowp   = (int*)alloc(sizeof(int) * (N_NODES + 1));
    int*    cursor = (int*)alloc(sizeof(int) * N_NODES);
    int*    csr    = (int*)alloc(sizeof(int) * N_EDGES);
    int*    csre   = (int*)alloc(sizeof(int) * N_EDGES);
    int*    bsum   = (int*)alloc(sizeof(int) * 64);
    int*    boff   = (int*)alloc(sizeof(int) * 64);

    // zero all accumulation buffers every call (harness does not re-poison)
    hipMemsetAsync(deg, 0, sizeof(int) * N_NODES, stream);
    hipMemsetAsync(cursor, 0, sizeof(int) * N_NODES, stream);

    deg_hist_kernel<<<(N_EDGES + 255) / 256, 256, 0, stream>>>(eidx, deg);
    scan_part1_kernel<<<NSCB, 256, 0, stream>>>(deg, bsum);
    scan_part2_kernel<<<1, 64, 0, stream>>>(bsum, boff);
    scan_part3_kernel<<<NSCB, 256, 0, stream>>>(deg, boff, rowp);
    fill_csr_kernel<<<(N_EDGES + 255) / 256, 256, 0, stream>>>(eidx, rowp, cursor, csr, csre);
    ea_gather_kernel<<<(N_NODES + 7) / 8, 256, 0, stream>>>(edge_attr, rowp, csre, Ea);

    float* accs[3] = {accA, accB, accA};
    const float* X = x;
    for (int l = 0; l < 3; ++l) {
        hipMemsetAsync(cs, 0, sizeof(float) * HID * 2, stream);  // cs + cq
        float* acc = accs[l];
        if (l == 0) {
            gemm_v3_kernel<false><<<256, 1024, 0, stream>>>(
                X, Wn[l], bnb[l], Ea, We[l], be[l], deg, nullptr, nullptr, hbuf, acc);
        } else {
            gemm_v3_kernel<true><<<256, 1024, 0, stream>>>(
                X, Wn[l], bnb[l], Ea, We[l], be[l], deg, scale, shift, hbuf, acc);
        }
        gather_kernel<<<(N_NODES + 3) / 4, 256, 0, stream>>>(
            hbuf, rowp, csr, acc);
        stats_kernel<<<256, 256, 0, stream>>>(acc, cs, cq);
        prep_bn_kernel<<<1, 128, 0, stream>>>(cs, cq, gm[l], bt[l], scale, shift);
        X = acc;
    }
    pool_fc_kernel<<<NUM_GRAPHS, 256, 0, stream>>>(
        accs[2], scale, shift, batch, Wfc, bfc, out);
}

// Round 9
// 498.795 us; speedup vs baseline: 1.0814x; 1.0814x over previous
//
#include <hip/hip_runtime.h>

#define N_NODES 50000
#define N_EDGES 640000
#define HID 128
#define EDGE_DIM 32
#define NUM_GRAPHS 512
#define BN_EPS 1e-5f
#define NGRP8 6250     // N_NODES / 8 (exact)
#define NSCB 49        // ceil(N_NODES/1024)

typedef unsigned int uint32;
typedef unsigned short ushort16;

// round-to-nearest-even f32 -> bf16 bits
__device__ inline ushort16 f2bf(float x) {
    uint32 u = __float_as_uint(x);
    return (ushort16)((u + 0x7fff + ((u >> 16) & 1)) >> 16);
}

// ---------------------------------------------------------------------------
// deg[d] = number of edges with dst == d
// ---------------------------------------------------------------------------
__global__ void deg_hist_kernel(const int* __restrict__ eidx, int* __restrict__ deg) {
    int e = blockIdx.x * 256 + threadIdx.x;
    if (e >= N_EDGES) return;
    atomicAdd(&deg[eidx[N_EDGES + e]], 1);
}

// ---------------------------------------------------------------------------
// Parallel exclusive scan of deg -> rowp, 3 dispatches
// ---------------------------------------------------------------------------
__global__ void scan_part1_kernel(const int* __restrict__ deg, int* __restrict__ bsum) {
    __shared__ int ts[256];
    int tid = threadIdx.x;
    int base = blockIdx.x * 1024 + tid * 4;
    int s = 0;
    #pragma unroll
    for (int j = 0; j < 4; ++j) { int i = base + j; if (i < N_NODES) s += deg[i]; }
    ts[tid] = s;
    __syncthreads();
    for (int off = 128; off > 0; off >>= 1) {
        if (tid < off) ts[tid] += ts[tid + off];
        __syncthreads();
    }
    if (tid == 0) bsum[blockIdx.x] = ts[0];
}

__global__ void scan_part2_kernel(const int* __restrict__ bsum, int* __restrict__ boff) {
    __shared__ int b[64];
    int t = threadIdx.x;
    b[t] = (t < NSCB) ? bsum[t] : 0;
    __syncthreads();
    if (t == 0) {
        int run = 0;
        for (int i = 0; i < NSCB; ++i) { int x = b[i]; b[i] = run; run += x; }
    }
    __syncthreads();
    if (t < NSCB) boff[t] = b[t];
}

__global__ void scan_part3_kernel(const int* __restrict__ deg, const int* __restrict__ boff,
                                  int* __restrict__ rowp) {
    __shared__ int ts[256];
    int tid = threadIdx.x;
    int base = blockIdx.x * 1024 + tid * 4;
    int v[4];
    int s = 0;
    #pragma unroll
    for (int j = 0; j < 4; ++j) {
        int i = base + j;
        v[j] = (i < N_NODES) ? deg[i] : 0;
        s += v[j];
    }
    ts[tid] = s;
    __syncthreads();
    for (int off = 1; off < 256; off <<= 1) {
        int t = (tid >= off) ? ts[tid - off] : 0;
        __syncthreads();
        ts[tid] += t;
        __syncthreads();
    }
    int excl = boff[blockIdx.x] + ts[tid] - s;
    #pragma unroll
    for (int j = 0; j < 4; ++j) {
        int i = base + j;
        if (i < N_NODES) rowp[i] = excl;
        excl += v[j];
    }
    if (blockIdx.x == 0 && tid == 0) rowp[N_NODES] = N_EDGES;
}

// CSR fill: csr_src[p] = source node, csr_eid[p] = edge id
__global__ void fill_csr_kernel(const int* __restrict__ eidx,
                                const int* __restrict__ rowp,
                                int* __restrict__ cursor,
                                int* __restrict__ csr_src,
                                int* __restrict__ csr_eid) {
    int e = blockIdx.x * 256 + threadIdx.x;
    if (e >= N_EDGES) return;
    int d = eidx[N_EDGES + e];
    int pos = rowp[d] + atomicAdd(&cursor[d], 1);
    csr_src[pos] = eidx[e];
    csr_eid[pos] = e;
}

// ---------------------------------------------------------------------------
// Ea[d] = sum of edge_attr rows with dst == d (CSR gather, no float atomics)
// half-wave per node, 4-deep index prefetch + 4 independent accumulators
// ---------------------------------------------------------------------------
__global__ __launch_bounds__(256) void ea_gather_kernel(
        const float* __restrict__ edge_attr,
        const int* __restrict__ rowp,
        const int* __restrict__ csr_eid,
        float* __restrict__ Ea) {
    int node = blockIdx.x * 8 + (threadIdx.x >> 5);
    int c = threadIdx.x & 31;
    if (node >= N_NODES) return;
    int beg = rowp[node], end = rowp[node + 1];
    float s0 = 0.f, s1 = 0.f, s2 = 0.f, s3 = 0.f;
    int p = beg;
    for (; p + 4 <= end; p += 4) {
        int e0 = csr_eid[p],     e1 = csr_eid[p + 1];
        int e2 = csr_eid[p + 2], e3 = csr_eid[p + 3];
        s0 += edge_attr[e0 * EDGE_DIM + c];
        s1 += edge_attr[e1 * EDGE_DIM + c];
        s2 += edge_attr[e2 * EDGE_DIM + c];
        s3 += edge_attr[e3 * EDGE_DIM + c];
    }
    for (; p < end; ++p)
        s0 += edge_attr[csr_eid[p] * EDGE_DIM + c];
    Ea[node * EDGE_DIM + c] = (s0 + s1) + (s2 + s3);
}

// ---------------------------------------------------------------------------
// In-place BN+ReLU: x = relu(x*scale[c] + shift[c])  (pre-pass for layers 2,3)
// ---------------------------------------------------------------------------
__global__ __launch_bounds__(256) void bnrelu_kernel(
        float* __restrict__ x,
        const float* __restrict__ scale, const float* __restrict__ shift) {
    int t = blockIdx.x * 256 + threadIdx.x;        // t indexes float4 slots
    if (t >= N_NODES * 32) return;
    int c4 = (t & 31) * 4;
    float4 v = *(float4*)&x[t * 4];
    float4 s = *(const float4*)&scale[c4];
    float4 h = *(const float4*)&shift[c4];
    v.x = fmaxf(0.f, v.x * s.x + h.x);
    v.y = fmaxf(0.f, v.y * s.y + h.y);
    v.z = fmaxf(0.f, v.z * s.z + h.z);
    v.w = fmaxf(0.f, v.w * s.w + h.w);
    *(float4*)&x[t * 4] = v;
}

// ---------------------------------------------------------------------------
// GEMM v4 — scalar-broadcast X. Per layer (X already BN'd by pre-pass):
//   h[i]   = X[i] @ Wn + bn      -> bf16 (gather operand)
//   acc[i] = h[i] + Ea[i] @ We + deg[i] * be   -> fp32
// 1024 threads = 16 waves; wave owns 8 rows (wave-uniform); lane owns cols
// (2L, 2L+1). W from LDS (1 ds_read_b64 per k); X via SCALAR loads
// (readfirstlane-hoisted row base -> s_load_dwordx4), consumed as the
// single legal SGPR operand of v_fma. No X LDS, no readlane, no broadcasts
// on the vector-memory path. LDS: 64K Wn + 16K We = 80 KB -> 2 blocks/CU.
// Wave-work interleave g = wid*512 + bid balances 6250 groups over blocks.
// ---------------------------------------------------------------------------
__global__ __launch_bounds__(1024, 8) void gemm_v4_kernel(
        const float* __restrict__ X, const float* __restrict__ Wn,
        const float* __restrict__ bnb,
        const float* __restrict__ Ea, const float* __restrict__ We,
        const float* __restrict__ be, const int* __restrict__ deg,
        uint32* __restrict__ hb32, float* __restrict__ acc) {
    __shared__ __align__(16) float Wns[128 * 128];   // [k][c], 64 KB
    __shared__ __align__(16) float Wes[32 * 128];    // [k][c], 16 KB
    const int tid = threadIdx.x;

    #pragma unroll
    for (int j = 0; j < 4; ++j)
        ((float4*)Wns)[tid + j * 1024] = ((const float4*)Wn)[tid + j * 1024];
    ((float4*)Wes)[tid] = ((const float4*)We)[tid];
    __syncthreads();

    const int wid = tid >> 6, L = tid & 63;
    const int g = wid * 512 + blockIdx.x;    // balanced interleave
    if (g >= NGRP8) return;
    const int r0u = __builtin_amdgcn_readfirstlane(g * 8);   // uniform row base
    const float* __restrict__ Xrow = X + (size_t)r0u * 128;
    const float* __restrict__ Erow = Ea + (size_t)r0u * 32;

    float2 a2[8];
    #pragma unroll
    for (int r = 0; r < 8; ++r) a2[r] = make_float2(0.f, 0.f);

    // ---- node GEMM: K = 128, k-quad steps ----
    #pragma unroll 2
    for (int kb = 0; kb < 128; kb += 4) {
        float4 xr[8];
        #pragma unroll
        for (int r = 0; r < 8; ++r)
            xr[r] = *(const float4*)&Xrow[r * 128 + kb];   // uniform -> s_load
        #pragma unroll
        for (int dk = 0; dk < 4; ++dk) {
            float2 w = *(const float2*)&Wns[(kb + dk) * 128 + 2 * L];
            #pragma unroll
            for (int r = 0; r < 8; ++r) {
                float xv = ((const float*)&xr[r])[dk];
                a2[r].x = fmaf(xv, w.x, a2[r].x);
                a2[r].y = fmaf(xv, w.y, a2[r].y);
            }
        }
    }

    // h = a + bn -> packed bf16 (hb32[row*64 + u] holds cols 2u,2u+1)
    const float2 bn2 = *(const float2*)&bnb[2 * L];
    #pragma unroll
    for (int r = 0; r < 8; ++r) {
        a2[r].x += bn2.x; a2[r].y += bn2.y;
        hb32[(r0u + r) * 64 + L] =
            (uint32)f2bf(a2[r].x) | ((uint32)f2bf(a2[r].y) << 16);
    }

    // ---- edge GEMM: K = 32 ----
    #pragma unroll 2
    for (int kb = 0; kb < 32; kb += 4) {
        float4 er[8];
        #pragma unroll
        for (int r = 0; r < 8; ++r)
            er[r] = *(const float4*)&Erow[r * 32 + kb];    // uniform -> s_load
        #pragma unroll
        for (int dk = 0; dk < 4; ++dk) {
            float2 w = *(const float2*)&Wes[(kb + dk) * 128 + 2 * L];
            #pragma unroll
            for (int r = 0; r < 8; ++r) {
                float xv = ((const float*)&er[r])[dk];
                a2[r].x = fmaf(xv, w.x, a2[r].x);
                a2[r].y = fmaf(xv, w.y, a2[r].y);
            }
        }
    }

    const float2 be2 = *(const float2*)&be[2 * L];
    #pragma unroll
    for (int r = 0; r < 8; ++r) {
        float dg = (float)deg[r0u + r];
        float2 o;
        o.x = a2[r].x + dg * be2.x;
        o.y = a2[r].y + dg * be2.y;
        *(float2*)&acc[(r0u + r) * 128 + 2 * L] = o;
    }
}

// ---------------------------------------------------------------------------
// acc[d] += sum over CSR edges of h_bf16[src]
// one WAVE (64 lanes) per node; lane covers cols (2*lane, 2*lane+1);
// 4-deep index prefetch + 4 independent partial sums for MLP
// ---------------------------------------------------------------------------
__global__ __launch_bounds__(256) void gather_kernel(
        const uint32* __restrict__ h32,      // 64 uints (=128 bf16) per row
        const int* __restrict__ rowp, const int* __restrict__ csr_src,
        float* __restrict__ acc) {
    int node = blockIdx.x * 4 + (threadIdx.x >> 6);
    if (node >= N_NODES) return;
    int lane = threadIdx.x & 63;
    int beg = rowp[node], end = rowp[node + 1];
    float sx0 = 0.f, sy0 = 0.f, sx1 = 0.f, sy1 = 0.f;
    float sx2 = 0.f, sy2 = 0.f, sx3 = 0.f, sy3 = 0.f;
    int p = beg;
    for (; p + 4 <= end; p += 4) {
        int i0 = csr_src[p], i1 = csr_src[p + 1];
        int i2 = csr_src[p + 2], i3 = csr_src[p + 3];
        uint32 v0 = h32[i0 * 64 + lane];
        uint32 v1 = h32[i1 * 64 + lane];
        uint32 v2 = h32[i2 * 64 + lane];
        uint32 v3 = h32[i3 * 64 + lane];
        sx0 += __uint_as_float(v0 << 16); sy0 += __uint_as_float(v0 & 0xffff0000u);
        sx1 += __uint_as_float(v1 << 16); sy1 += __uint_as_float(v1 & 0xffff0000u);
        sx2 += __uint_as_float(v2 << 16); sy2 += __uint_as_float(v2 & 0xffff0000u);
        sx3 += __uint_as_float(v3 << 16); sy3 += __uint_as_float(v3 & 0xffff0000u);
    }
    for (; p < end; ++p) {
        uint32 v = h32[csr_src[p] * 64 + lane];
        sx0 += __uint_as_float(v << 16); sy0 += __uint_as_float(v & 0xffff0000u);
    }
    float2* ap = (float2*)&acc[node * 128 + lane * 2];
    float2 a = *ap;
    a.x += (sx0 + sx1) + (sx2 + sx3);
    a.y += (sy0 + sy1) + (sy2 + sy3);
    *ap = a;
}

// per-column sum / sumsq over all nodes
__global__ void stats_kernel(const float* __restrict__ acc,
                             float* __restrict__ cs, float* __restrict__ cq) {
    int c = threadIdx.x & 127;
    int rg = threadIdx.x >> 7;
    float s = 0.f, q = 0.f;
    for (int r = blockIdx.x * 2 + rg; r < N_NODES; r += gridDim.x * 2) {
        float v = acc[r * 128 + c];
        s += v; q += v * v;
    }
    unsafeAtomicAdd(&cs[c], s);
    unsafeAtomicAdd(&cq[c], q);
}

// scale/shift from column stats: y = x*scale[c] + shift[c]
__global__ void prep_bn_kernel(const float* __restrict__ cs, const float* __restrict__ cq,
                               const float* __restrict__ gamma, const float* __restrict__ beta,
                               float* __restrict__ scale, float* __restrict__ shift) {
    int c = threadIdx.x;
    const float invN = 1.0f / (float)N_NODES;
    float m = cs[c] * invN;
    float var = cq[c] * invN - m * m;
    float sc = gamma[c] * rsqrtf(var + BN_EPS);
    scale[c] = sc;
    shift[c] = beta[c] - m * sc;
}

// ---------------------------------------------------------------------------
// One block per graph (batch is sorted): binary-search node range, apply
// layer-3 BN+ReLU inline, mean-pool, then the 128->2 FC. No atomics.
// ---------------------------------------------------------------------------
__global__ __launch_bounds__(256) void pool_fc_kernel(
        const float* __restrict__ acc,
        const float* __restrict__ scale, const float* __restrict__ shift,
        const int* __restrict__ batch,
        const float* __restrict__ Wfc, const float* __restrict__ bfc,
        float* __restrict__ out) {
    __shared__ float ps[256];
    int g = blockIdx.x;
    int lo = 0, hi = N_NODES;
    while (lo < hi) { int mid = (lo + hi) >> 1; if (batch[mid] < g) lo = mid + 1; else hi = mid; }
    int start = lo;
    hi = N_NODES;
    while (lo < hi) { int mid = (lo + hi) >> 1; if (batch[mid] < g + 1) lo = mid + 1; else hi = mid; }
    int end = lo;

    int c = threadIdx.x & 127;
    int half = threadIdx.x >> 7;
    float sc = scale[c], sh = shift[c];
    float s = 0.f;
    for (int r = start + half; r < end; r += 2)
        s += fmaxf(0.f, acc[r * 128 + c] * sc + sh);
    ps[threadIdx.x] = s;
    __syncthreads();
    if (half == 0)
        ps[c] = (ps[c] + ps[c + 128]) / fmaxf((float)(end - start), 1.0f);
    __syncthreads();
    if (threadIdx.x < 2) {
        int o = threadIdx.x;
        float t = 0.f;
        #pragma unroll 16
        for (int cc = 0; cc < 128; ++cc) t += ps[cc] * Wfc[cc * 2 + o];
        out[g * 2 + o] = t + bfc[o];
    }
}

// ---------------------------------------------------------------------------
extern "C" void kernel_launch(void* const* d_in, const int* in_sizes, int n_in,
                              void* d_out, int out_size, void* d_ws, size_t ws_size,
                              hipStream_t stream) {
    const float* x         = (const float*)d_in[0];
    const float* edge_attr = (const float*)d_in[1];
    const int*   eidx      = (const int*)d_in[2];
    const int*   batch     = (const int*)d_in[3];
    const float* Wn[3]  = {(const float*)d_in[4],  (const float*)d_in[8],  (const float*)d_in[12]};
    const float* bnb[3] = {(const float*)d_in[5],  (const float*)d_in[9],  (const float*)d_in[13]};
    const float* We[3]  = {(const float*)d_in[6],  (const float*)d_in[10], (const float*)d_in[14]};
    const float* be[3]  = {(const float*)d_in[7],  (const float*)d_in[11], (const float*)d_in[15]};
    const float* gm[3]  = {(const float*)d_in[16], (const float*)d_in[18], (const float*)d_in[20]};
    const float* bt[3]  = {(const float*)d_in[17], (const float*)d_in[19], (const float*)d_in[21]};
    const float* Wfc = (const float*)d_in[22];
    const float* bfc = (const float*)d_in[23];
    float* out = (float*)d_out;

    char* p = (char*)d_ws;
    auto alloc = [&](size_t bytes) {
        char* q = p;
        p += (bytes + 255) & ~size_t(255);
        return q;
    };
    float*  Ea     = (float*)alloc(sizeof(float) * N_NODES * EDGE_DIM);
    uint32* hbuf   = (uint32*)alloc(sizeof(uint32) * N_NODES * 64);   // bf16x2 packed
    float*  accA   = (float*)alloc(sizeof(float) * N_NODES * HID);
    float*  accB   = (float*)alloc(sizeof(float) * N_NODES * HID);
    float*  cs     = (float*)alloc(sizeof(float) * HID);    // cs and cq contiguous
    float*  cq     = (float*)alloc(sizeof(float) * HID);
    float*  scale  = (float*)alloc(sizeof(float) * HID);
    float*  shift  = (float*)alloc(sizeof(float) * HID);
    int*    deg    = (int*)alloc(sizeof(int) * N_NODES);
    int*    rowp   = (int*)alloc(sizeof(int) * (N_NODES + 1));
    int*    cursor = (int*)alloc(sizeof(int) * N_NODES);
    int*    csr    = (int*)alloc(sizeof(int) * N_EDGES);
    int*    csre   = (int*)alloc(sizeof(int) * N_EDGES);
    int*    bsum   = (int*)alloc(sizeof(int) * 64);
    int*    boff   = (int*)alloc(sizeof(int) * 64);

    // zero all accumulation buffers every call (harness does not re-poison)
    hipMemsetAsync(deg, 0, sizeof(int) * N_NODES, stream);
    hipMemsetAsync(cursor, 0, sizeof(int) * N_NODES, stream);

    deg_hist_kernel<<<(N_EDGES + 255) / 256, 256, 0, stream>>>(eidx, deg);
    scan_part1_kernel<<<NSCB, 256, 0, stream>>>(deg, bsum);
    scan_part2_kernel<<<1, 64, 0, stream>>>(bsum, boff);
    scan_part3_kernel<<<NSCB, 256, 0, stream>>>(deg, boff, rowp);
    fill_csr_kernel<<<(N_EDGES + 255) / 256, 256, 0, stream>>>(eidx, rowp, cursor, csr, csre);
    ea_gather_kernel<<<(N_NODES + 7) / 8, 256, 0, stream>>>(edge_attr, rowp, csre, Ea);

    float* accs[3] = {accA, accB, accA};
    const float* X = x;
    for (int l = 0; l < 3; ++l) {
        hipMemsetAsync(cs, 0, sizeof(float) * HID * 2, stream);  // cs + cq
        float* acc = accs[l];
        if (l > 0) {
            // in-place BN+ReLU on previous layer's acc, then it becomes X
            bnrelu_kernel<<<(N_NODES * 32 + 255) / 256, 256, 0, stream>>>(
                accs[l - 1], scale, shift);
            X = accs[l - 1];
        }
        gemm_v4_kernel<<<512, 1024, 0, stream>>>(
            X, Wn[l], bnb[l], Ea, We[l], be[l], deg, hbuf, acc);
        gather_kernel<<<(N_NODES + 3) / 4, 256, 0, stream>>>(
            hbuf, rowp, csr, acc);
        stats_kernel<<<256, 256, 0, stream>>>(acc, cs, cq);
        prep_bn_kernel<<<1, 128, 0, stream>>>(cs, cq, gm[l], bt[l], scale, shift);
    }
    pool_fc_kernel<<<NUM_GRAPHS, 256, 0, stream>>>(
        accs[2], scale, shift, batch, Wfc, bfc, out);
}

// Round 10
// 420.951 us; speedup vs baseline: 1.2814x; 1.1849x over previous
//
#include <hip/hip_runtime.h>

#define N_NODES 50000
#define N_EDGES 640000
#define HID 128
#define EDGE_DIM 32
#define NUM_GRAPHS 512
#define BN_EPS 1e-5f
#define NGRP16 3125    // N_NODES / 16 (exact)
#define NSCB 49        // ceil(N_NODES/1024)

typedef unsigned int uint32;
typedef unsigned short ushort;
typedef __attribute__((ext_vector_type(8))) short short8;   // 8 bf16 (4 VGPR)
typedef __attribute__((ext_vector_type(4))) float f32x4;    // MFMA accum

// round-to-nearest-even f32 -> bf16 bits
__device__ inline ushort f2bf(float x) {
    uint32 u = __float_as_uint(x);
    return (ushort)((u + 0x7fff + ((u >> 16) & 1)) >> 16);
}

// ---------------------------------------------------------------------------
// deg[d] = number of edges with dst == d
// ---------------------------------------------------------------------------
__global__ void deg_hist_kernel(const int* __restrict__ eidx, int* __restrict__ deg) {
    int e = blockIdx.x * 256 + threadIdx.x;
    if (e >= N_EDGES) return;
    atomicAdd(&deg[eidx[N_EDGES + e]], 1);
}

// ---------------------------------------------------------------------------
// Parallel exclusive scan of deg -> rowp, 3 dispatches
// ---------------------------------------------------------------------------
__global__ void scan_part1_kernel(const int* __restrict__ deg, int* __restrict__ bsum) {
    __shared__ int ts[256];
    int tid = threadIdx.x;
    int base = blockIdx.x * 1024 + tid * 4;
    int s = 0;
    #pragma unroll
    for (int j = 0; j < 4; ++j) { int i = base + j; if (i < N_NODES) s += deg[i]; }
    ts[tid] = s;
    __syncthreads();
    for (int off = 128; off > 0; off >>= 1) {
        if (tid < off) ts[tid] += ts[tid + off];
        __syncthreads();
    }
    if (tid == 0) bsum[blockIdx.x] = ts[0];
}

__global__ void scan_part2_kernel(const int* __restrict__ bsum, int* __restrict__ boff) {
    __shared__ int b[64];
    int t = threadIdx.x;
    b[t] = (t < NSCB) ? bsum[t] : 0;
    __syncthreads();
    if (t == 0) {
        int run = 0;
        for (int i = 0; i < NSCB; ++i) { int x = b[i]; b[i] = run; run += x; }
    }
    __syncthreads();
    if (t < NSCB) boff[t] = b[t];
}

__global__ void scan_part3_kernel(const int* __restrict__ deg, const int* __restrict__ boff,
                                  int* __restrict__ rowp) {
    __shared__ int ts[256];
    int tid = threadIdx.x;
    int base = blockIdx.x * 1024 + tid * 4;
    int v[4];
    int s = 0;
    #pragma unroll
    for (int j = 0; j < 4; ++j) {
        int i = base + j;
        v[j] = (i < N_NODES) ? deg[i] : 0;
        s += v[j];
    }
    ts[tid] = s;
    __syncthreads();
    for (int off = 1; off < 256; off <<= 1) {
        int t = (tid >= off) ? ts[tid - off] : 0;
        __syncthreads();
        ts[tid] += t;
        __syncthreads();
    }
    int excl = boff[blockIdx.x] + ts[tid] - s;
    #pragma unroll
    for (int j = 0; j < 4; ++j) {
        int i = base + j;
        if (i < N_NODES) rowp[i] = excl;
        excl += v[j];
    }
    if (blockIdx.x == 0 && tid == 0) rowp[N_NODES] = N_EDGES;
}

// CSR fill: csr_src[p] = source node, csr_eid[p] = edge id
__global__ void fill_csr_kernel(const int* __restrict__ eidx,
                                const int* __restrict__ rowp,
                                int* __restrict__ cursor,
                                int* __restrict__ csr_src,
                                int* __restrict__ csr_eid) {
    int e = blockIdx.x * 256 + threadIdx.x;
    if (e >= N_EDGES) return;
    int d = eidx[N_EDGES + e];
    int pos = rowp[d] + atomicAdd(&cursor[d], 1);
    csr_src[pos] = eidx[e];
    csr_eid[pos] = e;
}

// ---------------------------------------------------------------------------
// Eab[d] = bf16( sum of edge_attr rows with dst == d )   (GEMM A-operand)
// half-wave per node, 4-deep index prefetch for MLP
// ---------------------------------------------------------------------------
__global__ __launch_bounds__(256) void ea_gather_kernel(
        const float* __restrict__ edge_attr,
        const int* __restrict__ rowp,
        const int* __restrict__ csr_eid,
        ushort* __restrict__ Eab) {
    int node = blockIdx.x * 8 + (threadIdx.x >> 5);
    int c = threadIdx.x & 31;
    if (node >= N_NODES) return;
    int beg = rowp[node], end = rowp[node + 1];
    float s0 = 0.f, s1 = 0.f, s2 = 0.f, s3 = 0.f;
    int p = beg;
    for (; p + 4 <= end; p += 4) {
        int e0 = csr_eid[p],     e1 = csr_eid[p + 1];
        int e2 = csr_eid[p + 2], e3 = csr_eid[p + 3];
        s0 += edge_attr[e0 * EDGE_DIM + c];
        s1 += edge_attr[e1 * EDGE_DIM + c];
        s2 += edge_attr[e2 * EDGE_DIM + c];
        s3 += edge_attr[e3 * EDGE_DIM + c];
    }
    for (; p < end; ++p)
        s0 += edge_attr[csr_eid[p] * EDGE_DIM + c];
    Eab[node * EDGE_DIM + c] = f2bf((s0 + s1) + (s2 + s3));
}

// ---------------------------------------------------------------------------
// Pack Wn (128x128) and We (32x128) into per-fragment bf16 layout for
// mfma_f32_16x16x32_bf16. B frag: lane l holds B[k][n], n = nt*16 + (l&15),
// k = kb*32 + (l>>4)*8 + j (j=0..7, contiguous short8).
//   Wnp[(nt*4 + kb)*64 + l]  (nt=0..7, kb=0..3)
//   Wep[nt*64 + l]           (nt=0..7, single K step)
// ---------------------------------------------------------------------------
__global__ __launch_bounds__(256) void pack_w_kernel(
        const float* __restrict__ Wn, const float* __restrict__ We,
        short8* __restrict__ Wnp, short8* __restrict__ Wep) {
    int t = blockIdx.x * 256 + threadIdx.x;
    if (t < 2048) {
        int l = t & 63, rest = t >> 6;
        int kb = rest & 3, nt = rest >> 2;
        int col = nt * 16 + (l & 15);
        int k0 = kb * 32 + (l >> 4) * 8;
        short8 v;
        #pragma unroll
        for (int j = 0; j < 8; ++j) v[j] = (short)f2bf(Wn[(k0 + j) * 128 + col]);
        Wnp[t] = v;
    } else if (t < 2560) {
        int e = t - 2048;
        int l = e & 63, nt = e >> 6;
        int col = nt * 16 + (l & 15);
        int k0 = (l >> 4) * 8;
        short8 v;
        #pragma unroll
        for (int j = 0; j < 8; ++j) v[j] = (short)f2bf(We[(k0 + j) * 128 + col]);
        Wep[e] = v;
    }
}

// ---------------------------------------------------------------------------
// X -> bf16 (optionally applying BN+ReLU of the previous layer).
// thread handles 8 consecutive floats = one short8 store.
// ---------------------------------------------------------------------------
template <bool BN>
__global__ __launch_bounds__(256) void tobf_kernel(
        const float* __restrict__ in,
        const float* __restrict__ scale, const float* __restrict__ shift,
        short8* __restrict__ xb) {
    int t = blockIdx.x * 256 + threadIdx.x;      // < N_NODES*16
    if (t >= N_NODES * 16) return;
    int c8 = (t & 15) * 8;
    const float* src = in + (size_t)t * 8;
    float v[8];
    *(float4*)&v[0] = *(const float4*)src;
    *(float4*)&v[4] = *(const float4*)(src + 4);
    short8 o;
    #pragma unroll
    for (int j = 0; j < 8; ++j) {
        float y = v[j];
        if (BN) y = fmaxf(0.f, y * scale[c8 + j] + shift[c8 + j]);
        o[j] = (short)f2bf(y);
    }
    xb[t] = o;
}

// ---------------------------------------------------------------------------
// MFMA GEMM. Per layer:
//   h[i]   = X[i] @ Wn + bn                 -> bf16 h16 (gather operand)
//   acc[i] = h[i] + Ea[i] @ We + deg[i]*be  -> fp32
// One wave per 16 rows x 128 cols: 8 N-tiles x (4+1) K-steps = 40 mfma.
// A frags from bf16 xb / Eab (row-major, contiguous short8 per lane);
// B frags from packed Wnp/Wep (40 KB total, L1-resident). No LDS.
// C/D layout (m89-verified): col = lane&15, row = (lane>>4)*4 + reg.
// ---------------------------------------------------------------------------
__global__ __launch_bounds__(256) void gemm_mfma_kernel(
        const ushort* __restrict__ xb, const short8* __restrict__ Wnp,
        const float* __restrict__ bnb,
        const ushort* __restrict__ eab, const short8* __restrict__ Wep,
        const float* __restrict__ be, const int* __restrict__ deg,
        ushort* __restrict__ h16, float* __restrict__ acc) {
    const int wid = threadIdx.x >> 6, L = threadIdx.x & 63;
    const int g = blockIdx.x * 4 + wid;
    if (g >= NGRP16) return;                    // wave-uniform exit
    const int r0 = g * 16;
    const int m = L & 15, kq = L >> 4;

    // A fragments: lane reads row r0+m, k = kb*32 + kq*8 .. +8
    short8 afr[4];
    const ushort* xrow = xb + (size_t)(r0 + m) * 128 + kq * 8;
    #pragma unroll
    for (int kb = 0; kb < 4; ++kb)
        afr[kb] = *(const short8*)(xrow + kb * 32);

    f32x4 d[8];
    #pragma unroll
    for (int nt = 0; nt < 8; ++nt) d[nt] = (f32x4)(0.f);

    // node GEMM: K = 128
    #pragma unroll
    for (int kb = 0; kb < 4; ++kb) {
        #pragma unroll
        for (int nt = 0; nt < 8; ++nt) {
            short8 b = Wnp[(nt * 4 + kb) * 64 + L];
            d[nt] = __builtin_amdgcn_mfma_f32_16x16x32_bf16(afr[kb], b, d[nt], 0, 0, 0);
        }
    }

    float bnv[8], bev[8];
    #pragma unroll
    for (int nt = 0; nt < 8; ++nt) {
        bnv[nt] = bnb[nt * 16 + m];
        bev[nt] = be[nt * 16 + m];
    }

    // h = node + bn -> bf16 (h16[row*128+col]: same bytes as gather's packed u32)
    #pragma unroll
    for (int nt = 0; nt < 8; ++nt) {
        #pragma unroll
        for (int i = 0; i < 4; ++i)
            h16[(size_t)(r0 + kq * 4 + i) * 128 + nt * 16 + m] =
                f2bf(d[nt][i] + bnv[nt]);
    }

    // edge GEMM: K = 32 (one step)
    short8 ae = *(const short8*)(eab + (size_t)(r0 + m) * 32 + kq * 8);
    #pragma unroll
    for (int nt = 0; nt < 8; ++nt)
        d[nt] = __builtin_amdgcn_mfma_f32_16x16x32_bf16(ae, Wep[nt * 64 + L], d[nt], 0, 0, 0);

    float dg[4];
    #pragma unroll
    for (int i = 0; i < 4; ++i) dg[i] = (float)deg[r0 + kq * 4 + i];

    #pragma unroll
    for (int nt = 0; nt < 8; ++nt) {
        #pragma unroll
        for (int i = 0; i < 4; ++i)
            acc[(size_t)(r0 + kq * 4 + i) * 128 + nt * 16 + m] =
                d[nt][i] + bnv[nt] + dg[i] * bev[nt];
    }
}

// ---------------------------------------------------------------------------
// acc[d] += sum over CSR edges of h_bf16[src]
// one WAVE per node; lane covers cols (2*lane, 2*lane+1); 4-deep MLP
// ---------------------------------------------------------------------------
__global__ __launch_bounds__(256) void gather_kernel(
        const uint32* __restrict__ h32,      // 64 uints (=128 bf16) per row
        const int* __restrict__ rowp, const int* __restrict__ csr_src,
        float* __restrict__ acc) {
    int node = blockIdx.x * 4 + (threadIdx.x >> 6);
    if (node >= N_NODES) return;
    int lane = threadIdx.x & 63;
    int beg = rowp[node], end = rowp[node + 1];
    float sx0 = 0.f, sy0 = 0.f, sx1 = 0.f, sy1 = 0.f;
    float sx2 = 0.f, sy2 = 0.f, sx3 = 0.f, sy3 = 0.f;
    int p = beg;
    for (; p + 4 <= end; p += 4) {
        int i0 = csr_src[p], i1 = csr_src[p + 1];
        int i2 = csr_src[p + 2], i3 = csr_src[p + 3];
        uint32 v0 = h32[i0 * 64 + lane];
        uint32 v1 = h32[i1 * 64 + lane];
        uint32 v2 = h32[i2 * 64 + lane];
        uint32 v3 = h32[i3 * 64 + lane];
        sx0 += __uint_as_float(v0 << 16); sy0 += __uint_as_float(v0 & 0xffff0000u);
        sx1 += __uint_as_float(v1 << 16); sy1 += __uint_as_float(v1 & 0xffff0000u);
        sx2 += __uint_as_float(v2 << 16); sy2 += __uint_as_float(v2 & 0xffff0000u);
        sx3 += __uint_as_float(v3 << 16); sy3 += __uint_as_float(v3 & 0xffff0000u);
    }
    for (; p < end; ++p) {
        uint32 v = h32[csr_src[p] * 64 + lane];
        sx0 += __uint_as_float(v << 16); sy0 += __uint_as_float(v & 0xffff0000u);
    }
    float2* ap = (float2*)&acc[node * 128 + lane * 2];
    float2 a = *ap;
    a.x += (sx0 + sx1) + (sx2 + sx3);
    a.y += (sy0 + sy1) + (sy2 + sy3);
    *ap = a;
}

// per-column sum / sumsq over all nodes
__global__ void stats_kernel(const float* __restrict__ acc,
                             float* __restrict__ cs, float* __restrict__ cq) {
    int c = threadIdx.x & 127;
    int rg = threadIdx.x >> 7;
    float s = 0.f, q = 0.f;
    for (int r = blockIdx.x * 2 + rg; r < N_NODES; r += gridDim.x * 2) {
        float v = acc[r * 128 + c];
        s += v; q += v * v;
    }
    unsafeAtomicAdd(&cs[c], s);
    unsafeAtomicAdd(&cq[c], q);
}

// scale/shift from column stats: y = x*scale[c] + shift[c]
__global__ void prep_bn_kernel(const float* __restrict__ cs, const float* __restrict__ cq,
                               const float* __restrict__ gamma, const float* __restrict__ beta,
                               float* __restrict__ scale, float* __restrict__ shift) {
    int c = threadIdx.x;
    const float invN = 1.0f / (float)N_NODES;
    float m = cs[c] * invN;
    float var = cq[c] * invN - m * m;
    float sc = gamma[c] * rsqrtf(var + BN_EPS);
    scale[c] = sc;
    shift[c] = beta[c] - m * sc;
}

// ---------------------------------------------------------------------------
// One block per graph (batch is sorted): binary-search node range, apply
// layer-3 BN+ReLU inline, mean-pool, then the 128->2 FC. No atomics.
// ---------------------------------------------------------------------------
__global__ __launch_bounds__(256) void pool_fc_kernel(
        const float* __restrict__ acc,
        const float* __restrict__ scale, const float* __restrict__ shift,
        const int* __restrict__ batch,
        const float* __restrict__ Wfc, const float* __restrict__ bfc,
        float* __restrict__ out) {
    __shared__ float ps[256];
    int g = blockIdx.x;
    int lo = 0, hi = N_NODES;
    while (lo < hi) { int mid = (lo + hi) >> 1; if (batch[mid] < g) lo = mid + 1; else hi = mid; }
    int start = lo;
    hi = N_NODES;
    while (lo < hi) { int mid = (lo + hi) >> 1; if (batch[mid] < g + 1) lo = mid + 1; else hi = mid; }
    int end = lo;

    int c = threadIdx.x & 127;
    int half = threadIdx.x >> 7;
    float sc = scale[c], sh = shift[c];
    float s = 0.f;
    for (int r = start + half; r < end; r += 2)
        s += fmaxf(0.f, acc[r * 128 + c] * sc + sh);
    ps[threadIdx.x] = s;
    __syncthreads();
    if (half == 0)
        ps[c] = (ps[c] + ps[c + 128]) / fmaxf((float)(end - start), 1.0f);
    __syncthreads();
    if (threadIdx.x < 2) {
        int o = threadIdx.x;
        float t = 0.f;
        #pragma unroll 16
        for (int cc = 0; cc < 128; ++cc) t += ps[cc] * Wfc[cc * 2 + o];
        out[g * 2 + o] = t + bfc[o];
    }
}

// ---------------------------------------------------------------------------
extern "C" void kernel_launch(void* const* d_in, const int* in_sizes, int n_in,
                              void* d_out, int out_size, void* d_ws, size_t ws_size,
                              hipStream_t stream) {
    const float* x         = (const float*)d_in[0];
    const float* edge_attr = (const float*)d_in[1];
    const int*   eidx      = (const int*)d_in[2];
    const int*   batch     = (const int*)d_in[3];
    const float* Wn[3]  = {(const float*)d_in[4],  (const float*)d_in[8],  (const float*)d_in[12]};
    const float* bnb[3] = {(const float*)d_in[5],  (const float*)d_in[9],  (const float*)d_in[13]};
    const float* We[3]  = {(const float*)d_in[6],  (const float*)d_in[10], (const float*)d_in[14]};
    const float* be[3]  = {(const float*)d_in[7],  (const float*)d_in[11], (const float*)d_in[15]};
    const float* gm[3]  = {(const float*)d_in[16], (const float*)d_in[18], (const float*)d_in[20]};
    const float* bt[3]  = {(const float*)d_in[17], (const float*)d_in[19], (const float*)d_in[21]};
    const float* Wfc = (const float*)d_in[22];
    const float* bfc = (const float*)d_in[23];
    float* out = (float*)d_out;

    char* p = (char*)d_ws;
    auto alloc = [&](size_t bytes) {
        char* q = p;
        p += (bytes + 255) & ~size_t(255);
        return q;
    };
    short8* xb     = (short8*)alloc(sizeof(ushort) * N_NODES * HID);      // bf16 X
    ushort* h16    = (ushort*)alloc(sizeof(ushort) * N_NODES * HID);      // bf16 h
    ushort* Eab    = (ushort*)alloc(sizeof(ushort) * N_NODES * EDGE_DIM); // bf16 Ea
    float*  accA   = (float*)alloc(sizeof(float) * N_NODES * HID);
    float*  accB   = (float*)alloc(sizeof(float) * N_NODES * HID);
    float*  cs     = (float*)alloc(sizeof(float) * HID);    // cs and cq contiguous
    float*  cq     = (float*)alloc(sizeof(float) * HID);
    float*  scale  = (float*)alloc(sizeof(float) * HID);
    float*  shift  = (float*)alloc(sizeof(float) * HID);
    int*    deg    = (int*)alloc(sizeof(int) * N_NODES);
    int*    rowp   = (int*)alloc(sizeof(int) * (N_NODES + 1));
    int*    cursor = (int*)alloc(sizeof(int) * N_NODES);
    int*    csr    = (int*)alloc(sizeof(int) * N_EDGES);
    int*    csre   = (int*)alloc(sizeof(int) * N_EDGES);
    int*    bsum   = (int*)alloc(sizeof(int) * 64);
    int*    boff   = (int*)alloc(sizeof(int) * 64);
    short8* Wnp[3]; short8* Wep[3];
    for (int l = 0; l < 3; ++l) {
        Wnp[l] = (short8*)alloc(sizeof(short8) * 2048);
        Wep[l] = (short8*)alloc(sizeof(short8) * 512);
    }

    // zero all accumulation buffers every call (harness does not re-poison)
    hipMemsetAsync(deg, 0, sizeof(int) * N_NODES, stream);
    hipMemsetAsync(cursor, 0, sizeof(int) * N_NODES, stream);

    deg_hist_kernel<<<(N_EDGES + 255) / 256, 256, 0, stream>>>(eidx, deg);
    scan_part1_kernel<<<NSCB, 256, 0, stream>>>(deg, bsum);
    scan_part2_kernel<<<1, 64, 0, stream>>>(bsum, boff);
    scan_part3_kernel<<<NSCB, 256, 0, stream>>>(deg, boff, rowp);
    fill_csr_kernel<<<(N_EDGES + 255) / 256, 256, 0, stream>>>(eidx, rowp, cursor, csr, csre);
    ea_gather_kernel<<<(N_NODES + 7) / 8, 256, 0, stream>>>(edge_attr, rowp, csre, Eab);
    for (int l = 0; l < 3; ++l)
        pack_w_kernel<<<10, 256, 0, stream>>>(Wn[l], We[l], Wnp[l], Wep[l]);

    float* accs[3] = {accA, accB, accA};
    for (int l = 0; l < 3; ++l) {
        hipMemsetAsync(cs, 0, sizeof(float) * HID * 2, stream);  // cs + cq
        float* acc = accs[l];
        if (l == 0) {
            tobf_kernel<false><<<(N_NODES * 16 + 255) / 256, 256, 0, stream>>>(
                x, nullptr, nullptr, xb);
        } else {
            tobf_kernel<true><<<(N_NODES * 16 + 255) / 256, 256, 0, stream>>>(
                accs[l - 1], scale, shift, xb);
        }
        gemm_mfma_kernel<<<(NGRP16 + 3) / 4, 256, 0, stream>>>(
            (const ushort*)xb, Wnp[l], bnb[l], Eab, Wep[l], be[l], deg, h16, acc);
        gather_kernel<<<(N_NODES + 3) / 4, 256, 0, stream>>>(
            (const uint32*)h16, rowp, csr, acc);
        stats_kernel<<<256, 256, 0, stream>>>(acc, cs, cq);
        prep_bn_kernel<<<1, 128, 0, stream>>>(cs, cq, gm[l], bt[l], scale, shift);
    }
    pool_fc_kernel<<<NUM_GRAPHS, 256, 0, stream>>>(
        accs[2], scale, shift, batch, Wfc, bfc, out);
}

// Round 11
// 419.263 us; speedup vs baseline: 1.2865x; 1.0040x over previous
//
#include <hip/hip_runtime.h>

#define N_NODES 50000
#define N_EDGES 640000
#define HID 128
#define EDGE_DIM 32
#define NUM_GRAPHS 512
#define BN_EPS 1e-5f
#define NGRP16 3125    // N_NODES / 16 (exact)
#define NSCB 49        // ceil(N_NODES/1024)

typedef unsigned int uint32;
typedef unsigned long long uint64;
typedef unsigned short ushort;
typedef __attribute__((ext_vector_type(8))) short short8;   // 8 bf16 (4 VGPR)
typedef __attribute__((ext_vector_type(4))) float f32x4;    // MFMA accum

// round-to-nearest-even f32 -> bf16 bits
__device__ inline ushort f2bf(float x) {
    uint32 u = __float_as_uint(x);
    return (ushort)((u + 0x7fff + ((u >> 16) & 1)) >> 16);
}

// ---------------------------------------------------------------------------
// deg[d] = number of edges with dst == d
// ---------------------------------------------------------------------------
__global__ void deg_hist_kernel(const int* __restrict__ eidx, int* __restrict__ deg) {
    int e = blockIdx.x * 256 + threadIdx.x;
    if (e >= N_EDGES) return;
    atomicAdd(&deg[eidx[N_EDGES + e]], 1);
}

// ---------------------------------------------------------------------------
// Parallel exclusive scan of deg -> rowp, 3 dispatches
// ---------------------------------------------------------------------------
__global__ void scan_part1_kernel(const int* __restrict__ deg, int* __restrict__ bsum) {
    __shared__ int ts[256];
    int tid = threadIdx.x;
    int base = blockIdx.x * 1024 + tid * 4;
    int s = 0;
    #pragma unroll
    for (int j = 0; j < 4; ++j) { int i = base + j; if (i < N_NODES) s += deg[i]; }
    ts[tid] = s;
    __syncthreads();
    for (int off = 128; off > 0; off >>= 1) {
        if (tid < off) ts[tid] += ts[tid + off];
        __syncthreads();
    }
    if (tid == 0) bsum[blockIdx.x] = ts[0];
}

__global__ void scan_part2_kernel(const int* __restrict__ bsum, int* __restrict__ boff) {
    __shared__ int b[64];
    int t = threadIdx.x;
    b[t] = (t < NSCB) ? bsum[t] : 0;
    __syncthreads();
    if (t == 0) {
        int run = 0;
        for (int i = 0; i < NSCB; ++i) { int x = b[i]; b[i] = run; run += x; }
    }
    __syncthreads();
    if (t < NSCB) boff[t] = b[t];
}

__global__ void scan_part3_kernel(const int* __restrict__ deg, const int* __restrict__ boff,
                                  int* __restrict__ rowp) {
    __shared__ int ts[256];
    int tid = threadIdx.x;
    int base = blockIdx.x * 1024 + tid * 4;
    int v[4];
    int s = 0;
    #pragma unroll
    for (int j = 0; j < 4; ++j) {
        int i = base + j;
        v[j] = (i < N_NODES) ? deg[i] : 0;
        s += v[j];
    }
    ts[tid] = s;
    __syncthreads();
    for (int off = 1; off < 256; off <<= 1) {
        int t = (tid >= off) ? ts[tid - off] : 0;
        __syncthreads();
        ts[tid] += t;
        __syncthreads();
    }
    int excl = boff[blockIdx.x] + ts[tid] - s;
    #pragma unroll
    for (int j = 0; j < 4; ++j) {
        int i = base + j;
        if (i < N_NODES) rowp[i] = excl;
        excl += v[j];
    }
    if (blockIdx.x == 0 && tid == 0) rowp[N_NODES] = N_EDGES;
}

// ---------------------------------------------------------------------------
// CSR fill (packed): csr_pk[p] = (eid << 32) | src  — ONE 8B scatter per edge
// (two separate 4B scatters doubled the dirtied-line count -> 70 MB HBM WR)
// ---------------------------------------------------------------------------
__global__ void fill_csr_kernel(const int* __restrict__ eidx,
                                const int* __restrict__ rowp,
                                int* __restrict__ cursor,
                                uint64* __restrict__ csr_pk) {
    int e = blockIdx.x * 256 + threadIdx.x;
    if (e >= N_EDGES) return;
    int d = eidx[N_EDGES + e];
    int pos = rowp[d] + atomicAdd(&cursor[d], 1);
    csr_pk[pos] = ((uint64)(uint32)e << 32) | (uint32)eidx[e];
}

// ---------------------------------------------------------------------------
// Eab[d] = bf16( sum of edge_attr rows with dst == d )   (GEMM A-operand)
// half-wave per node, 4-deep index prefetch for MLP
// ---------------------------------------------------------------------------
__global__ __launch_bounds__(256) void ea_gather_kernel(
        const float* __restrict__ edge_attr,
        const int* __restrict__ rowp,
        const uint64* __restrict__ csr_pk,
        ushort* __restrict__ Eab) {
    int node = blockIdx.x * 8 + (threadIdx.x >> 5);
    int c = threadIdx.x & 31;
    if (node >= N_NODES) return;
    int beg = rowp[node], end = rowp[node + 1];
    float s0 = 0.f, s1 = 0.f, s2 = 0.f, s3 = 0.f;
    int p = beg;
    for (; p + 4 <= end; p += 4) {
        int e0 = (int)(csr_pk[p]     >> 32);
        int e1 = (int)(csr_pk[p + 1] >> 32);
        int e2 = (int)(csr_pk[p + 2] >> 32);
        int e3 = (int)(csr_pk[p + 3] >> 32);
        s0 += edge_attr[e0 * EDGE_DIM + c];
        s1 += edge_attr[e1 * EDGE_DIM + c];
        s2 += edge_attr[e2 * EDGE_DIM + c];
        s3 += edge_attr[e3 * EDGE_DIM + c];
    }
    for (; p < end; ++p)
        s0 += edge_attr[(int)(csr_pk[p] >> 32) * EDGE_DIM + c];
    Eab[node * EDGE_DIM + c] = f2bf((s0 + s1) + (s2 + s3));
}

// ---------------------------------------------------------------------------
// Pack Wn (128x128) and We (32x128) into per-fragment bf16 layout for
// mfma_f32_16x16x32_bf16. B frag: lane l holds B[k][n], n = nt*16 + (l&15),
// k = kb*32 + (l>>4)*8 + j (j=0..7, contiguous short8).
// ---------------------------------------------------------------------------
__global__ __launch_bounds__(256) void pack_w_kernel(
        const float* __restrict__ Wn, const float* __restrict__ We,
        short8* __restrict__ Wnp, short8* __restrict__ Wep) {
    int t = blockIdx.x * 256 + threadIdx.x;
    if (t < 2048) {
        int l = t & 63, rest = t >> 6;
        int kb = rest & 3, nt = rest >> 2;
        int col = nt * 16 + (l & 15);
        int k0 = kb * 32 + (l >> 4) * 8;
        short8 v;
        #pragma unroll
        for (int j = 0; j < 8; ++j) v[j] = (short)f2bf(Wn[(k0 + j) * 128 + col]);
        Wnp[t] = v;
    } else if (t < 2560) {
        int e = t - 2048;
        int l = e & 63, nt = e >> 6;
        int col = nt * 16 + (l & 15);
        int k0 = (l >> 4) * 8;
        short8 v;
        #pragma unroll
        for (int j = 0; j < 8; ++j) v[j] = (short)f2bf(We[(k0 + j) * 128 + col]);
        Wep[e] = v;
    }
}

// ---------------------------------------------------------------------------
// X -> bf16 (optionally applying BN+ReLU of the previous layer).
// thread handles 8 consecutive floats = one short8 store.
// ---------------------------------------------------------------------------
template <bool BN>
__global__ __launch_bounds__(256) void tobf_kernel(
        const float* __restrict__ in,
        const float* __restrict__ scale, const float* __restrict__ shift,
        short8* __restrict__ xb) {
    int t = blockIdx.x * 256 + threadIdx.x;      // < N_NODES*16
    if (t >= N_NODES * 16) return;
    int c8 = (t & 15) * 8;
    const float* src = in + (size_t)t * 8;
    float v[8];
    *(float4*)&v[0] = *(const float4*)src;
    *(float4*)&v[4] = *(const float4*)(src + 4);
    short8 o;
    #pragma unroll
    for (int j = 0; j < 8; ++j) {
        float y = v[j];
        if (BN) y = fmaxf(0.f, y * scale[c8 + j] + shift[c8 + j]);
        o[j] = (short)f2bf(y);
    }
    xb[t] = o;
}

// ---------------------------------------------------------------------------
// MFMA GEMM. Per layer:
//   h[i]   = X[i] @ Wn + bn                 -> bf16 h16 (gather operand)
//   acc[i] = h[i] + Ea[i] @ We + deg[i]*be  -> fp32
// One wave per 16 rows x 128 cols: 8 N-tiles x (4+1) K-steps = 40 mfma.
// A frags from bf16 xb / Eab; B frags from packed Wnp/Wep (L1-resident).
// C/D layout (m89-verified): col = lane&15, row = (lane>>4)*4 + reg.
// ---------------------------------------------------------------------------
__global__ __launch_bounds__(256) void gemm_mfma_kernel(
        const ushort* __restrict__ xb, const short8* __restrict__ Wnp,
        const float* __restrict__ bnb,
        const ushort* __restrict__ eab, const short8* __restrict__ Wep,
        const float* __restrict__ be, const int* __restrict__ deg,
        ushort* __restrict__ h16, float* __restrict__ acc) {
    const int wid = threadIdx.x >> 6, L = threadIdx.x & 63;
    const int g = blockIdx.x * 4 + wid;
    if (g >= NGRP16) return;                    // wave-uniform exit
    const int r0 = g * 16;
    const int m = L & 15, kq = L >> 4;

    // A fragments: lane reads row r0+m, k = kb*32 + kq*8 .. +8
    short8 afr[4];
    const ushort* xrow = xb + (size_t)(r0 + m) * 128 + kq * 8;
    #pragma unroll
    for (int kb = 0; kb < 4; ++kb)
        afr[kb] = *(const short8*)(xrow + kb * 32);

    f32x4 d[8];
    #pragma unroll
    for (int nt = 0; nt < 8; ++nt) d[nt] = (f32x4)(0.f);

    // node GEMM: K = 128
    #pragma unroll
    for (int kb = 0; kb < 4; ++kb) {
        #pragma unroll
        for (int nt = 0; nt < 8; ++nt) {
            short8 b = Wnp[(nt * 4 + kb) * 64 + L];
            d[nt] = __builtin_amdgcn_mfma_f32_16x16x32_bf16(afr[kb], b, d[nt], 0, 0, 0);
        }
    }

    float bnv[8], bev[8];
    #pragma unroll
    for (int nt = 0; nt < 8; ++nt) {
        bnv[nt] = bnb[nt * 16 + m];
        bev[nt] = be[nt * 16 + m];
    }

    // h = node + bn -> bf16 (h16[row*128+col]: same bytes as gather's packed u32)
    #pragma unroll
    for (int nt = 0; nt < 8; ++nt) {
        #pragma unroll
        for (int i = 0; i < 4; ++i)
            h16[(size_t)(r0 + kq * 4 + i) * 128 + nt * 16 + m] =
                f2bf(d[nt][i] + bnv[nt]);
    }

    // edge GEMM: K = 32 (one step)
    short8 ae = *(const short8*)(eab + (size_t)(r0 + m) * 32 + kq * 8);
    #pragma unroll
    for (int nt = 0; nt < 8; ++nt)
        d[nt] = __builtin_amdgcn_mfma_f32_16x16x32_bf16(ae, Wep[nt * 64 + L], d[nt], 0, 0, 0);

    float dg[4];
    #pragma unroll
    for (int i = 0; i < 4; ++i) dg[i] = (float)deg[r0 + kq * 4 + i];

    #pragma unroll
    for (int nt = 0; nt < 8; ++nt) {
        #pragma unroll
        for (int i = 0; i < 4; ++i)
            acc[(size_t)(r0 + kq * 4 + i) * 128 + nt * 16 + m] =
                d[nt][i] + bnv[nt] + dg[i] * bev[nt];
    }
}

// ---------------------------------------------------------------------------
// acc[d] += sum over CSR edges of h_bf16[src]
// one WAVE per node; lane covers cols (2*lane, 2*lane+1); 4-deep MLP
// ---------------------------------------------------------------------------
__global__ __launch_bounds__(256) void gather_kernel(
        const uint32* __restrict__ h32,      // 64 uints (=128 bf16) per row
        const int* __restrict__ rowp, const uint64* __restrict__ csr_pk,
        float* __restrict__ acc) {
    int node = blockIdx.x * 4 + (threadIdx.x >> 6);
    if (node >= N_NODES) return;
    int lane = threadIdx.x & 63;
    int beg = rowp[node], end = rowp[node + 1];
    float sx0 = 0.f, sy0 = 0.f, sx1 = 0.f, sy1 = 0.f;
    float sx2 = 0.f, sy2 = 0.f, sx3 = 0.f, sy3 = 0.f;
    int p = beg;
    for (; p + 4 <= end; p += 4) {
        int i0 = (int)(uint32)csr_pk[p];
        int i1 = (int)(uint32)csr_pk[p + 1];
        int i2 = (int)(uint32)csr_pk[p + 2];
        int i3 = (int)(uint32)csr_pk[p + 3];
        uint32 v0 = h32[i0 * 64 + lane];
        uint32 v1 = h32[i1 * 64 + lane];
        uint32 v2 = h32[i2 * 64 + lane];
        uint32 v3 = h32[i3 * 64 + lane];
        sx0 += __uint_as_float(v0 << 16); sy0 += __uint_as_float(v0 & 0xffff0000u);
        sx1 += __uint_as_float(v1 << 16); sy1 += __uint_as_float(v1 & 0xffff0000u);
        sx2 += __uint_as_float(v2 << 16); sy2 += __uint_as_float(v2 & 0xffff0000u);
        sx3 += __uint_as_float(v3 << 16); sy3 += __uint_as_float(v3 & 0xffff0000u);
    }
    for (; p < end; ++p) {
        uint32 v = h32[(int)(uint32)csr_pk[p] * 64 + lane];
        sx0 += __uint_as_float(v << 16); sy0 += __uint_as_float(v & 0xffff0000u);
    }
    float2* ap = (float2*)&acc[node * 128 + lane * 2];
    float2 a = *ap;
    a.x += (sx0 + sx1) + (sx2 + sx3);
    a.y += (sy0 + sy1) + (sy2 + sy3);
    *ap = a;
}

// per-column sum / sumsq over all nodes
__global__ void stats_kernel(const float* __restrict__ acc,
                             float* __restrict__ cs, float* __restrict__ cq) {
    int c = threadIdx.x & 127;
    int rg = threadIdx.x >> 7;
    float s = 0.f, q = 0.f;
    for (int r = blockIdx.x * 2 + rg; r < N_NODES; r += gridDim.x * 2) {
        float v = acc[r * 128 + c];
        s += v; q += v * v;
    }
    unsafeAtomicAdd(&cs[c], s);
    unsafeAtomicAdd(&cq[c], q);
}

// scale/shift from column stats: y = x*scale[c] + shift[c]
__global__ void prep_bn_kernel(const float* __restrict__ cs, const float* __restrict__ cq,
                               const float* __restrict__ gamma, const float* __restrict__ beta,
                               float* __restrict__ scale, float* __restrict__ shift) {
    int c = threadIdx.x;
    const float invN = 1.0f / (float)N_NODES;
    float m = cs[c] * invN;
    float var = cq[c] * invN - m * m;
    float sc = gamma[c] * rsqrtf(var + BN_EPS);
    scale[c] = sc;
    shift[c] = beta[c] - m * sc;
}

// ---------------------------------------------------------------------------
// One block per graph (batch is sorted): binary-search node range, apply
// layer-3 BN+ReLU inline, mean-pool, then the 128->2 FC. No atomics.
// ---------------------------------------------------------------------------
__global__ __launch_bounds__(256) void pool_fc_kernel(
        const float* __restrict__ acc,
        const float* __restrict__ scale, const float* __restrict__ shift,
        const int* __restrict__ batch,
        const float* __restrict__ Wfc, const float* __restrict__ bfc,
        float* __restrict__ out) {
    __shared__ float ps[256];
    int g = blockIdx.x;
    int lo = 0, hi = N_NODES;
    while (lo < hi) { int mid = (lo + hi) >> 1; if (batch[mid] < g) lo = mid + 1; else hi = mid; }
    int start = lo;
    hi = N_NODES;
    while (lo < hi) { int mid = (lo + hi) >> 1; if (batch[mid] < g + 1) lo = mid + 1; else hi = mid; }
    int end = lo;

    int c = threadIdx.x & 127;
    int half = threadIdx.x >> 7;
    float sc = scale[c], sh = shift[c];
    float s = 0.f;
    for (int r = start + half; r < end; r += 2)
        s += fmaxf(0.f, acc[r * 128 + c] * sc + sh);
    ps[threadIdx.x] = s;
    __syncthreads();
    if (half == 0)
        ps[c] = (ps[c] + ps[c + 128]) / fmaxf((float)(end - start), 1.0f);
    __syncthreads();
    if (threadIdx.x < 2) {
        int o = threadIdx.x;
        float t = 0.f;
        #pragma unroll 16
        for (int cc = 0; cc < 128; ++cc) t += ps[cc] * Wfc[cc * 2 + o];
        out[g * 2 + o] = t + bfc[o];
    }
}

// ---------------------------------------------------------------------------
extern "C" void kernel_launch(void* const* d_in, const int* in_sizes, int n_in,
                              void* d_out, int out_size, void* d_ws, size_t ws_size,
                              hipStream_t stream) {
    const float* x         = (const float*)d_in[0];
    const float* edge_attr = (const float*)d_in[1];
    const int*   eidx      = (const int*)d_in[2];
    const int*   batch     = (const int*)d_in[3];
    const float* Wn[3]  = {(const float*)d_in[4],  (const float*)d_in[8],  (const float*)d_in[12]};
    const float* bnb[3] = {(const float*)d_in[5],  (const float*)d_in[9],  (const float*)d_in[13]};
    const float* We[3]  = {(const float*)d_in[6],  (const float*)d_in[10], (const float*)d_in[14]};
    const float* be[3]  = {(const float*)d_in[7],  (const float*)d_in[11], (const float*)d_in[15]};
    const float* gm[3]  = {(const float*)d_in[16], (const float*)d_in[18], (const float*)d_in[20]};
    const float* bt[3]  = {(const float*)d_in[17], (const float*)d_in[19], (const float*)d_in[21]};
    const float* Wfc = (const float*)d_in[22];
    const float* bfc = (const float*)d_in[23];
    float* out = (float*)d_out;

    char* p = (char*)d_ws;
    auto alloc = [&](size_t bytes) {
        char* q = p;
        p += (bytes + 255) & ~size_t(255);
        return q;
    };
    short8* xb     = (short8*)alloc(sizeof(ushort) * N_NODES * HID);      // bf16 X
    ushort* h16    = (ushort*)alloc(sizeof(ushort) * N_NODES * HID);      // bf16 h
    ushort* Eab    = (ushort*)alloc(sizeof(ushort) * N_NODES * EDGE_DIM); // bf16 Ea
    float*  accA   = (float*)alloc(sizeof(float) * N_NODES * HID);
    float*  accB   = (float*)alloc(sizeof(float) * N_NODES * HID);
    float*  cs     = (float*)alloc(sizeof(float) * HID);    // cs and cq contiguous
    float*  cq     = (float*)alloc(sizeof(float) * HID);
    float*  scale  = (float*)alloc(sizeof(float) * HID);
    float*  shift  = (float*)alloc(sizeof(float) * HID);
    int*    deg    = (int*)alloc(sizeof(int) * N_NODES);
    int*    rowp   = (int*)alloc(sizeof(int) * (N_NODES + 1));
    int*    cursor = (int*)alloc(sizeof(int) * N_NODES);
    uint64* csr_pk = (uint64*)alloc(sizeof(uint64) * N_EDGES);
    int*    bsum   = (int*)alloc(sizeof(int) * 64);
    int*    boff   = (int*)alloc(sizeof(int) * 64);
    short8* Wnp[3]; short8* Wep[3];
    for (int l = 0; l < 3; ++l) {
        Wnp[l] = (short8*)alloc(sizeof(short8) * 2048);
        Wep[l] = (short8*)alloc(sizeof(short8) * 512);
    }

    // zero all accumulation buffers every call (harness does not re-poison)
    hipMemsetAsync(deg, 0, sizeof(int) * N_NODES, stream);
    hipMemsetAsync(cursor, 0, sizeof(int) * N_NODES, stream);

    deg_hist_kernel<<<(N_EDGES + 255) / 256, 256, 0, stream>>>(eidx, deg);
    scan_part1_kernel<<<NSCB, 256, 0, stream>>>(deg, bsum);
    scan_part2_kernel<<<1, 64, 0, stream>>>(bsum, boff);
    scan_part3_kernel<<<NSCB, 256, 0, stream>>>(deg, boff, rowp);
    fill_csr_kernel<<<(N_EDGES + 255) / 256, 256, 0, stream>>>(eidx, rowp, cursor, csr_pk);
    ea_gather_kernel<<<(N_NODES + 7) / 8, 256, 0, stream>>>(edge_attr, rowp, csr_pk, Eab);
    for (int l = 0; l < 3; ++l)
        pack_w_kernel<<<10, 256, 0, stream>>>(Wn[l], We[l], Wnp[l], Wep[l]);

    float* accs[3] = {accA, accB, accA};
    for (int l = 0; l < 3; ++l) {
        hipMemsetAsync(cs, 0, sizeof(float) * HID * 2, stream);  // cs + cq
        float* acc = accs[l];
        if (l == 0) {
            tobf_kernel<false><<<(N_NODES * 16 + 255) / 256, 256, 0, stream>>>(
                x, nullptr, nullptr, xb);
        } else {
            tobf_kernel<true><<<(N_NODES * 16 + 255) / 256, 256, 0, stream>>>(
                accs[l - 1], scale, shift, xb);
        }
        gemm_mfma_kernel<<<(NGRP16 + 3) / 4, 256, 0, stream>>>(
            (const ushort*)xb, Wnp[l], bnb[l], Eab, Wep[l], be[l], deg, h16, acc);
        gather_kernel<<<(N_NODES + 3) / 4, 256, 0, stream>>>(
            (const uint32*)h16, rowp, csr_pk, acc);
        stats_kernel<<<256, 256, 0, stream>>>(acc, cs, cq);
        prep_bn_kernel<<<1, 128, 0, stream>>>(cs, cq, gm[l], bt[l], scale, shift);
    }
    pool_fc_kernel<<<NUM_GRAPHS, 256, 0, stream>>>(
        accs[2], scale, shift, batch, Wfc, bfc, out);
}

// Round 12
// 402.596 us; speedup vs baseline: 1.3398x; 1.0414x over previous
//
#include <hip/hip_runtime.h>

#define N_NODES 50000
#define N_EDGES 640000
#define HID 128
#define EDGE_DIM 32
#define NUM_GRAPHS 512
#define BN_EPS 1e-5f
#define NGRP16 3125    // N_NODES / 16 (exact)
#define NSCB 49        // ceil(N_NODES/1024)

typedef unsigned int uint32;
typedef unsigned long long uint64;
typedef unsigned short ushort;
typedef __attribute__((ext_vector_type(8))) short short8;   // 8 bf16 (4 VGPR)
typedef __attribute__((ext_vector_type(4))) float f32x4;    // MFMA accum

// round-to-nearest-even f32 -> bf16 bits
__device__ inline ushort f2bf(float x) {
    uint32 u = __float_as_uint(x);
    return (ushort)((u + 0x7fff + ((u >> 16) & 1)) >> 16);
}

// ---------------------------------------------------------------------------
// deg[d] = number of edges with dst == d
// ---------------------------------------------------------------------------
__global__ void deg_hist_kernel(const int* __restrict__ eidx, int* __restrict__ deg) {
    int e = blockIdx.x * 256 + threadIdx.x;
    if (e >= N_EDGES) return;
    atomicAdd(&deg[eidx[N_EDGES + e]], 1);
}

// ---------------------------------------------------------------------------
// Parallel exclusive scan of deg -> rowp, 3 dispatches
// ---------------------------------------------------------------------------
__global__ void scan_part1_kernel(const int* __restrict__ deg, int* __restrict__ bsum) {
    __shared__ int ts[256];
    int tid = threadIdx.x;
    int base = blockIdx.x * 1024 + tid * 4;
    int s = 0;
    #pragma unroll
    for (int j = 0; j < 4; ++j) { int i = base + j; if (i < N_NODES) s += deg[i]; }
    ts[tid] = s;
    __syncthreads();
    for (int off = 128; off > 0; off >>= 1) {
        if (tid < off) ts[tid] += ts[tid + off];
        __syncthreads();
    }
    if (tid == 0) bsum[blockIdx.x] = ts[0];
}

__global__ void scan_part2_kernel(const int* __restrict__ bsum, int* __restrict__ boff) {
    __shared__ int b[64];
    int t = threadIdx.x;
    b[t] = (t < NSCB) ? bsum[t] : 0;
    __syncthreads();
    if (t == 0) {
        int run = 0;
        for (int i = 0; i < NSCB; ++i) { int x = b[i]; b[i] = run; run += x; }
    }
    __syncthreads();
    if (t < NSCB) boff[t] = b[t];
}

__global__ void scan_part3_kernel(const int* __restrict__ deg, const int* __restrict__ boff,
                                  int* __restrict__ rowp) {
    __shared__ int ts[256];
    int tid = threadIdx.x;
    int base = blockIdx.x * 1024 + tid * 4;
    int v[4];
    int s = 0;
    #pragma unroll
    for (int j = 0; j < 4; ++j) {
        int i = base + j;
        v[j] = (i < N_NODES) ? deg[i] : 0;
        s += v[j];
    }
    ts[tid] = s;
    __syncthreads();
    for (int off = 1; off < 256; off <<= 1) {
        int t = (tid >= off) ? ts[tid - off] : 0;
        __syncthreads();
        ts[tid] += t;
        __syncthreads();
    }
    int excl = boff[blockIdx.x] + ts[tid] - s;
    #pragma unroll
    for (int j = 0; j < 4; ++j) {
        int i = base + j;
        if (i < N_NODES) rowp[i] = excl;
        excl += v[j];
    }
    if (blockIdx.x == 0 && tid == 0) rowp[N_NODES] = N_EDGES;
}

// ---------------------------------------------------------------------------
// CSR fill (packed): csr_pk[p] = (eid << 32) | src — one 8B scatter per edge
// ---------------------------------------------------------------------------
__global__ void fill_csr_kernel(const int* __restrict__ eidx,
                                const int* __restrict__ rowp,
                                int* __restrict__ cursor,
                                uint64* __restrict__ csr_pk) {
    int e = blockIdx.x * 256 + threadIdx.x;
    if (e >= N_EDGES) return;
    int d = eidx[N_EDGES + e];
    int pos = rowp[d] + atomicAdd(&cursor[d], 1);
    csr_pk[pos] = ((uint64)(uint32)e << 32) | (uint32)eidx[e];
}

// ---------------------------------------------------------------------------
// Eab[d] = bf16( sum of edge_attr rows with dst == d )   (GEMM A-operand)
// ---------------------------------------------------------------------------
__global__ __launch_bounds__(256) void ea_gather_kernel(
        const float* __restrict__ edge_attr,
        const int* __restrict__ rowp,
        const uint64* __restrict__ csr_pk,
        ushort* __restrict__ Eab) {
    int node = blockIdx.x * 8 + (threadIdx.x >> 5);
    int c = threadIdx.x & 31;
    if (node >= N_NODES) return;
    int beg = rowp[node], end = rowp[node + 1];
    float s0 = 0.f, s1 = 0.f, s2 = 0.f, s3 = 0.f;
    int p = beg;
    for (; p + 4 <= end; p += 4) {
        int e0 = (int)(csr_pk[p]     >> 32);
        int e1 = (int)(csr_pk[p + 1] >> 32);
        int e2 = (int)(csr_pk[p + 2] >> 32);
        int e3 = (int)(csr_pk[p + 3] >> 32);
        s0 += edge_attr[e0 * EDGE_DIM + c];
        s1 += edge_attr[e1 * EDGE_DIM + c];
        s2 += edge_attr[e2 * EDGE_DIM + c];
        s3 += edge_attr[e3 * EDGE_DIM + c];
    }
    for (; p < end; ++p)
        s0 += edge_attr[(int)(csr_pk[p] >> 32) * EDGE_DIM + c];
    Eab[node * EDGE_DIM + c] = f2bf((s0 + s1) + (s2 + s3));
}

// ---------------------------------------------------------------------------
// Pack Wn (128x128) and We (32x128) into per-fragment bf16 layout for
// mfma_f32_16x16x32_bf16. B frag: lane l holds B[k][n], n = nt*16 + (l&15),
// k = kb*32 + (l>>4)*8 + j (j=0..7, contiguous short8).
// ---------------------------------------------------------------------------
__global__ __launch_bounds__(256) void pack_w_kernel(
        const float* __restrict__ Wn, const float* __restrict__ We,
        short8* __restrict__ Wnp, short8* __restrict__ Wep) {
    int t = blockIdx.x * 256 + threadIdx.x;
    if (t < 2048) {
        int l = t & 63, rest = t >> 6;
        int kb = rest & 3, nt = rest >> 2;
        int col = nt * 16 + (l & 15);
        int k0 = kb * 32 + (l >> 4) * 8;
        short8 v;
        #pragma unroll
        for (int j = 0; j < 8; ++j) v[j] = (short)f2bf(Wn[(k0 + j) * 128 + col]);
        Wnp[t] = v;
    } else if (t < 2560) {
        int e = t - 2048;
        int l = e & 63, nt = e >> 6;
        int col = nt * 16 + (l & 15);
        int k0 = (l >> 4) * 8;
        short8 v;
        #pragma unroll
        for (int j = 0; j < 8; ++j) v[j] = (short)f2bf(We[(k0 + j) * 128 + col]);
        Wep[e] = v;
    }
}

// ---------------------------------------------------------------------------
// MFMA GEMM, fp32-A inline BN+cast. Per layer:
//   xin    = BN ? relu(X*scale + shift) : X      (fp32, cast to bf16 in-reg)
//   h[i]   = xin[i] @ Wn + bn                 -> bf16 h16 (gather operand)
//   acc[i] = h[i] + Ea[i] @ We + deg[i]*be    -> fp32
// One wave per 16 rows x 128 cols: 8 N-tiles x (4+1) K-steps = 40 mfma.
// A built from fp32 X rows (read once -> no reuse -> no staging buffer);
// B frags from packed Wnp/Wep (L1-resident). No LDS.
// C/D layout (m89-verified): col = lane&15, row = (lane>>4)*4 + reg.
// ---------------------------------------------------------------------------
template <bool BN>
__global__ __launch_bounds__(256) void gemm_mfma_kernel(
        const float* __restrict__ X, const short8* __restrict__ Wnp,
        const float* __restrict__ bnb,
        const ushort* __restrict__ eab, const short8* __restrict__ Wep,
        const float* __restrict__ be, const int* __restrict__ deg,
        const float* __restrict__ scale, const float* __restrict__ shift,
        ushort* __restrict__ h16, float* __restrict__ acc) {
    const int wid = threadIdx.x >> 6, L = threadIdx.x & 63;
    const int g = blockIdx.x * 4 + wid;
    if (g >= NGRP16) return;                    // wave-uniform exit
    const int r0 = g * 16;
    const int m = L & 15, kq = L >> 4;

    // A fragments: lane reads fp32 row r0+m, k = kb*32 + kq*8 .. +8,
    // applies BN+ReLU inline, converts to bf16
    short8 afr[4];
    const float* xrow = X + (size_t)(r0 + m) * 128 + kq * 8;
    #pragma unroll
    for (int kb = 0; kb < 4; ++kb) {
        float v[8];
        *(float4*)&v[0] = *(const float4*)(xrow + kb * 32);
        *(float4*)&v[4] = *(const float4*)(xrow + kb * 32 + 4);
        if (BN) {
            float s[8], h[8];
            *(float4*)&s[0] = *(const float4*)(scale + kb * 32 + kq * 8);
            *(float4*)&s[4] = *(const float4*)(scale + kb * 32 + kq * 8 + 4);
            *(float4*)&h[0] = *(const float4*)(shift + kb * 32 + kq * 8);
            *(float4*)&h[4] = *(const float4*)(shift + kb * 32 + kq * 8 + 4);
            #pragma unroll
            for (int j = 0; j < 8; ++j)
                v[j] = fmaxf(0.f, v[j] * s[j] + h[j]);
        }
        short8 a;
        #pragma unroll
        for (int j = 0; j < 8; ++j) a[j] = (short)f2bf(v[j]);
        afr[kb] = a;
    }

    f32x4 d[8];
    #pragma unroll
    for (int nt = 0; nt < 8; ++nt) d[nt] = (f32x4)(0.f);

    // node GEMM: K = 128
    #pragma unroll
    for (int kb = 0; kb < 4; ++kb) {
        #pragma unroll
        for (int nt = 0; nt < 8; ++nt) {
            short8 b = Wnp[(nt * 4 + kb) * 64 + L];
            d[nt] = __builtin_amdgcn_mfma_f32_16x16x32_bf16(afr[kb], b, d[nt], 0, 0, 0);
        }
    }

    float bnv[8], bev[8];
    #pragma unroll
    for (int nt = 0; nt < 8; ++nt) {
        bnv[nt] = bnb[nt * 16 + m];
        bev[nt] = be[nt * 16 + m];
    }

    // h = node + bn -> bf16 (h16[row*128+col]: same bytes as gather's packed u32)
    #pragma unroll
    for (int nt = 0; nt < 8; ++nt) {
        #pragma unroll
        for (int i = 0; i < 4; ++i)
            h16[(size_t)(r0 + kq * 4 + i) * 128 + nt * 16 + m] =
                f2bf(d[nt][i] + bnv[nt]);
    }

    // edge GEMM: K = 32 (one step)
    short8 ae = *(const short8*)(eab + (size_t)(r0 + m) * 32 + kq * 8);
    #pragma unroll
    for (int nt = 0; nt < 8; ++nt)
        d[nt] = __builtin_amdgcn_mfma_f32_16x16x32_bf16(ae, Wep[nt * 64 + L], d[nt], 0, 0, 0);

    float dg[4];
    #pragma unroll
    for (int i = 0; i < 4; ++i) dg[i] = (float)deg[r0 + kq * 4 + i];

    #pragma unroll
    for (int nt = 0; nt < 8; ++nt) {
        #pragma unroll
        for (int i = 0; i < 4; ++i)
            acc[(size_t)(r0 + kq * 4 + i) * 128 + nt * 16 + m] =
                d[nt][i] + bnv[nt] + dg[i] * bev[nt];
    }
}

// ---------------------------------------------------------------------------
// acc[d] += sum over CSR edges of h_bf16[src]
// one WAVE per node; lane covers cols (2*lane, 2*lane+1); 8-deep MLP
// ---------------------------------------------------------------------------
__global__ __launch_bounds__(256) void gather_kernel(
        const uint32* __restrict__ h32,      // 64 uints (=128 bf16) per row
        const int* __restrict__ rowp, const uint64* __restrict__ csr_pk,
        float* __restrict__ acc) {
    int node = blockIdx.x * 4 + (threadIdx.x >> 6);
    if (node >= N_NODES) return;
    int lane = threadIdx.x & 63;
    int beg = rowp[node], end = rowp[node + 1];
    float sx[8] = {0.f,0.f,0.f,0.f,0.f,0.f,0.f,0.f};
    float sy[8] = {0.f,0.f,0.f,0.f,0.f,0.f,0.f,0.f};
    int p = beg;
    for (; p + 8 <= end; p += 8) {
        uint32 v[8];
        #pragma unroll
        for (int j = 0; j < 8; ++j)
            v[j] = h32[(int)(uint32)csr_pk[p + j] * 64 + lane];
        #pragma unroll
        for (int j = 0; j < 8; ++j) {
            sx[j] += __uint_as_float(v[j] << 16);
            sy[j] += __uint_as_float(v[j] & 0xffff0000u);
        }
    }
    for (; p + 4 <= end; p += 4) {
        uint32 v[4];
        #pragma unroll
        for (int j = 0; j < 4; ++j)
            v[j] = h32[(int)(uint32)csr_pk[p + j] * 64 + lane];
        #pragma unroll
        for (int j = 0; j < 4; ++j) {
            sx[j] += __uint_as_float(v[j] << 16);
            sy[j] += __uint_as_float(v[j] & 0xffff0000u);
        }
    }
    for (; p < end; ++p) {
        uint32 v = h32[(int)(uint32)csr_pk[p] * 64 + lane];
        sx[0] += __uint_as_float(v << 16);
        sy[0] += __uint_as_float(v & 0xffff0000u);
    }
    float2* ap = (float2*)&acc[node * 128 + lane * 2];
    float2 a = *ap;
    a.x += ((sx[0] + sx[1]) + (sx[2] + sx[3])) + ((sx[4] + sx[5]) + (sx[6] + sx[7]));
    a.y += ((sy[0] + sy[1]) + (sy[2] + sy[3])) + ((sy[4] + sy[5]) + (sy[6] + sy[7]));
    *ap = a;
}

// per-column sum / sumsq over all nodes
__global__ void stats_kernel(const float* __restrict__ acc,
                             float* __restrict__ cs, float* __restrict__ cq) {
    int c = threadIdx.x & 127;
    int rg = threadIdx.x >> 7;
    float s = 0.f, q = 0.f;
    for (int r = blockIdx.x * 2 + rg; r < N_NODES; r += gridDim.x * 2) {
        float v = acc[r * 128 + c];
        s += v; q += v * v;
    }
    unsafeAtomicAdd(&cs[c], s);
    unsafeAtomicAdd(&cq[c], q);
}

// scale/shift from column stats: y = x*scale[c] + shift[c]
__global__ void prep_bn_kernel(const float* __restrict__ cs, const float* __restrict__ cq,
                               const float* __restrict__ gamma, const float* __restrict__ beta,
                               float* __restrict__ scale, float* __restrict__ shift) {
    int c = threadIdx.x;
    const float invN = 1.0f / (float)N_NODES;
    float m = cs[c] * invN;
    float var = cq[c] * invN - m * m;
    float sc = gamma[c] * rsqrtf(var + BN_EPS);
    scale[c] = sc;
    shift[c] = beta[c] - m * sc;
}

// ---------------------------------------------------------------------------
// One block per graph (batch is sorted): binary-search node range, apply
// layer-3 BN+ReLU inline, mean-pool, then the 128->2 FC. No atomics.
// ---------------------------------------------------------------------------
__global__ __launch_bounds__(256) void pool_fc_kernel(
        const float* __restrict__ acc,
        const float* __restrict__ scale, const float* __restrict__ shift,
        const int* __restrict__ batch,
        const float* __restrict__ Wfc, const float* __restrict__ bfc,
        float* __restrict__ out) {
    __shared__ float ps[256];
    int g = blockIdx.x;
    int lo = 0, hi = N_NODES;
    while (lo < hi) { int mid = (lo + hi) >> 1; if (batch[mid] < g) lo = mid + 1; else hi = mid; }
    int start = lo;
    hi = N_NODES;
    while (lo < hi) { int mid = (lo + hi) >> 1; if (batch[mid] < g + 1) lo = mid + 1; else hi = mid; }
    int end = lo;

    int c = threadIdx.x & 127;
    int half = threadIdx.x >> 7;
    float sc = scale[c], sh = shift[c];
    float s = 0.f;
    for (int r = start + half; r < end; r += 2)
        s += fmaxf(0.f, acc[r * 128 + c] * sc + sh);
    ps[threadIdx.x] = s;
    __syncthreads();
    if (half == 0)
        ps[c] = (ps[c] + ps[c + 128]) / fmaxf((float)(end - start), 1.0f);
    __syncthreads();
    if (threadIdx.x < 2) {
        int o = threadIdx.x;
        float t = 0.f;
        #pragma unroll 16
        for (int cc = 0; cc < 128; ++cc) t += ps[cc] * Wfc[cc * 2 + o];
        out[g * 2 + o] = t + bfc[o];
    }
}

// ---------------------------------------------------------------------------
extern "C" void kernel_launch(void* const* d_in, const int* in_sizes, int n_in,
                              void* d_out, int out_size, void* d_ws, size_t ws_size,
                              hipStream_t stream) {
    const float* x         = (const float*)d_in[0];
    const float* edge_attr = (const float*)d_in[1];
    const int*   eidx      = (const int*)d_in[2];
    const int*   batch     = (const int*)d_in[3];
    const float* Wn[3]  = {(const float*)d_in[4],  (const float*)d_in[8],  (const float*)d_in[12]};
    const float* bnb[3] = {(const float*)d_in[5],  (const float*)d_in[9],  (const float*)d_in[13]};
    const float* We[3]  = {(const float*)d_in[6],  (const float*)d_in[10], (const float*)d_in[14]};
    const float* be[3]  = {(const float*)d_in[7],  (const float*)d_in[11], (const float*)d_in[15]};
    const float* gm[3]  = {(const float*)d_in[16], (const float*)d_in[18], (const float*)d_in[20]};
    const float* bt[3]  = {(const float*)d_in[17], (const float*)d_in[19], (const float*)d_in[21]};
    const float* Wfc = (const float*)d_in[22];
    const float* bfc = (const float*)d_in[23];
    float* out = (float*)d_out;

    char* p = (char*)d_ws;
    auto alloc = [&](size_t bytes) {
        char* q = p;
        p += (bytes + 255) & ~size_t(255);
        return q;
    };
    ushort* h16    = (ushort*)alloc(sizeof(ushort) * N_NODES * HID);      // bf16 h
    ushort* Eab    = (ushort*)alloc(sizeof(ushort) * N_NODES * EDGE_DIM); // bf16 Ea
    float*  accA   = (float*)alloc(sizeof(float) * N_NODES * HID);
    float*  accB   = (float*)alloc(sizeof(float) * N_NODES * HID);
    float*  cs     = (float*)alloc(sizeof(float) * HID);    // cs and cq contiguous
    float*  cq     = (float*)alloc(sizeof(float) * HID);
    float*  scale  = (float*)alloc(sizeof(float) * HID);
    float*  shift  = (float*)alloc(sizeof(float) * HID);
    int*    deg    = (int*)alloc(sizeof(int) * N_NODES);
    int*    rowp   = (int*)alloc(sizeof(int) * (N_NODES + 1));
    int*    cursor = (int*)alloc(sizeof(int) * N_NODES);
    uint64* csr_pk = (uint64*)alloc(sizeof(uint64) * N_EDGES);
    int*    bsum   = (int*)alloc(sizeof(int) * 64);
    int*    boff   = (int*)alloc(sizeof(int) * 64);
    short8* Wnp[3]; short8* Wep[3];
    for (int l = 0; l < 3; ++l) {
        Wnp[l] = (short8*)alloc(sizeof(short8) * 2048);
        Wep[l] = (short8*)alloc(sizeof(short8) * 512);
    }

    // zero all accumulation buffers every call (harness does not re-poison)
    hipMemsetAsync(deg, 0, sizeof(int) * N_NODES, stream);
    hipMemsetAsync(cursor, 0, sizeof(int) * N_NODES, stream);

    deg_hist_kernel<<<(N_EDGES + 255) / 256, 256, 0, stream>>>(eidx, deg);
    scan_part1_kernel<<<NSCB, 256, 0, stream>>>(deg, bsum);
    scan_part2_kernel<<<1, 64, 0, stream>>>(bsum, boff);
    scan_part3_kernel<<<NSCB, 256, 0, stream>>>(deg, boff, rowp);
    fill_csr_kernel<<<(N_EDGES + 255) / 256, 256, 0, stream>>>(eidx, rowp, cursor, csr_pk);
    ea_gather_kernel<<<(N_NODES + 7) / 8, 256, 0, stream>>>(edge_attr, rowp, csr_pk, Eab);
    for (int l = 0; l < 3; ++l)
        pack_w_kernel<<<10, 256, 0, stream>>>(Wn[l], We[l], Wnp[l], Wep[l]);

    float* accs[3] = {accA, accB, accA};
    for (int l = 0; l < 3; ++l) {
        hipMemsetAsync(cs, 0, sizeof(float) * HID * 2, stream);  // cs + cq
        float* acc = accs[l];
        const float* Xin = (l == 0) ? x : accs[l - 1];
        if (l == 0) {
            gemm_mfma_kernel<false><<<(NGRP16 + 3) / 4, 256, 0, stream>>>(
                Xin, Wnp[l], bnb[l], Eab, Wep[l], be[l], deg,
                nullptr, nullptr, h16, acc);
        } else {
            gemm_mfma_kernel<true><<<(NGRP16 + 3) / 4, 256, 0, stream>>>(
                Xin, Wnp[l], bnb[l], Eab, Wep[l], be[l], deg,
                scale, shift, h16, acc);
        }
        gather_kernel<<<(N_NODES + 3) / 4, 256, 0, stream>>>(
            (const uint32*)h16, rowp, csr_pk, acc);
        stats_kernel<<<256, 256, 0, stream>>>(acc, cs, cq);
        prep_bn_kernel<<<1, 128, 0, stream>>>(cs, cq, gm[l], bt[l], scale, shift);
    }
    pool_fc_kernel<<<NUM_GRAPHS, 256, 0, stream>>>(
        accs[2], scale, shift, batch, Wfc, bfc, out);
}